// Round 6
// baseline (986.077 us; speedup 1.0000x reference)
//
#include <hip/hip_runtime.h>
#include <hip/hip_bf16.h>

#define Bdim 256
#define Sdim 256
#define Hdim 1024
#define Vdim 128

#define NGRP 8    // batch groups
#define MB   32   // batch rows per group
#define NBLK 32   // blocks per group
#define NB   32   // neurons per block
#define VB   4    // vocab outputs per block (128/32)
#define GSTRIDE 64  // ints per group flag region (32 flags packed + 32 pad)

typedef __attribute__((ext_vector_type(8))) short short8;
typedef __attribute__((ext_vector_type(4))) float floatx4;

#define MFMA_BF16(a, b, c) __builtin_amdgcn_mfma_f32_16x16x32_bf16((a), (b), (c), 0, 0, 0)

__device__ __forceinline__ unsigned short f2bf(float f) {
  union { float f; unsigned u; } v; v.f = f;
  unsigned r = v.u + 0x7fffu + ((v.u >> 16) & 1u);
  return (unsigned short)(r >> 16);
}
__device__ __forceinline__ float bf2f(unsigned short s) {
  union { unsigned u; float f; } v; v.u = ((unsigned)s) << 16;
  return v.f;
}
__device__ __forceinline__ void split8(floatx4 a, floatx4 b, short8& hi, short8& lo) {
#pragma unroll
  for (int e = 0; e < 4; ++e) {
    unsigned short h0 = f2bf(a[e]);
    hi[e] = (short)h0;
    lo[e] = (short)f2bf(a[e] - bf2f(h0));
    unsigned short h1 = f2bf(b[e]);
    hi[e + 4] = (short)h1;
    lo[e + 4] = (short)f2bf(b[e] - bf2f(h1));
  }
}

// tanh via native exp + rcp: abs err <1e-6 (<< bf16 h quantization 2^-9).
__device__ __forceinline__ float fast_tanh(float x) {
  float e = __expf(2.0f * x);
  return 1.0f - 2.0f * __builtin_amdgcn_rcpf(e + 1.0f);
}

// IC-scope (cross-XCD safe) relaxed atomic 8B store: bypasses L2
__device__ __forceinline__ void ic_store(unsigned short* p, unsigned long long v) {
  __hip_atomic_store((unsigned long long*)p, v, __ATOMIC_RELAXED,
                     __HIP_MEMORY_SCOPE_AGENT);
}

// Issue 16 h-fragment loads PAIRWISE (A0[k],A1[k]) with NO trailing waitcnt.
// Consumption is gated per-chunk by CHUNK()'s vmcnt(14-2k) waits below, so
// rec-MFMAs pipeline behind the L2 broadcast instead of draining it first.
// PRECONDITION (round-3 lesson): the vmcnt queue must be EMPTY when this
// issues -- vmcnt retires IN ORDER, so any older in-flight load (e.g. a
// stale IC poll load) would gate every CHUNK wait behind its full latency.
#define LOADI16(SC)                                                        \
  asm volatile("global_load_dwordx4 %0, %16, off " SC "\n\t"               \
               "global_load_dwordx4 %8, %17, off " SC "\n\t"               \
               "global_load_dwordx4 %1, %16, off offset:64 " SC "\n\t"     \
               "global_load_dwordx4 %9, %17, off offset:64 " SC "\n\t"     \
               "global_load_dwordx4 %2, %16, off offset:128 " SC "\n\t"    \
               "global_load_dwordx4 %10, %17, off offset:128 " SC "\n\t"   \
               "global_load_dwordx4 %3, %16, off offset:192 " SC "\n\t"    \
               "global_load_dwordx4 %11, %17, off offset:192 " SC "\n\t"   \
               "global_load_dwordx4 %4, %16, off offset:256 " SC "\n\t"    \
               "global_load_dwordx4 %12, %17, off offset:256 " SC "\n\t"   \
               "global_load_dwordx4 %5, %16, off offset:320 " SC "\n\t"    \
               "global_load_dwordx4 %13, %17, off offset:320 " SC "\n\t"   \
               "global_load_dwordx4 %6, %16, off offset:384 " SC "\n\t"    \
               "global_load_dwordx4 %14, %17, off offset:384 " SC "\n\t"   \
               "global_load_dwordx4 %7, %16, off offset:448 " SC "\n\t"    \
               "global_load_dwordx4 %15, %17, off offset:448 " SC "\n\t"   \
               : "=&v"(A0[0]), "=&v"(A0[1]), "=&v"(A0[2]), "=&v"(A0[3]),   \
                 "=&v"(A0[4]), "=&v"(A0[5]), "=&v"(A0[6]), "=&v"(A0[7]),   \
                 "=&v"(A1[0]), "=&v"(A1[1]), "=&v"(A1[2]), "=&v"(A1[3]),   \
                 "=&v"(A1[4]), "=&v"(A1[5]), "=&v"(A1[6]), "=&v"(A1[7])    \
               : "v"(p0), "v"(p1)                                          \
               : "memory")

// Wait for chunk K's pair. Queue is clean at LOADI16 (drained post-poll), so
// <=14-2K outstanding => first 2(K+1) h-loads retired. "+v" ties create a
// data dep so MFMAs can't hoist above the wait (rule #18). hi-round then
// lo-round avoids back-to-back same-accumulator MFMAs.
#define CHUNK(K, VM)                                                         \
  asm volatile("s_waitcnt vmcnt(" #VM ")" : "+v"(A0[K]), "+v"(A1[K]));       \
  if (recc) {                                                                \
    accr[0][0] = MFMA_BF16(A0[K], Bhi[0][K], accr[0][0]);                    \
    accr[1][0] = MFMA_BF16(A1[K], Bhi[0][K], accr[1][0]);                    \
    accr[0][1] = MFMA_BF16(A0[K], Bhi[1][K], accr[0][1]);                    \
    accr[1][1] = MFMA_BF16(A1[K], Bhi[1][K], accr[1][1]);                    \
    accr[0][0] = MFMA_BF16(A0[K], Blo[0][K], accr[0][0]);                    \
    accr[1][0] = MFMA_BF16(A1[K], Blo[0][K], accr[1][0]);                    \
    accr[0][1] = MFMA_BF16(A0[K], Blo[1][K], accr[0][1]);                    \
    accr[1][1] = MFMA_BF16(A1[K], Blo[1][K], accr[1][1]);                    \
  }

// E2[v][k] = sum_h embed[v][h] * Wxh[k][h]   (128 x 1024), near-fp32 via hi/lo
__global__ __launch_bounds__(256) void e2_kernel(const float* __restrict__ embed,
                                                 const float* __restrict__ Wxh,
                                                 float* __restrict__ E2) {
  __shared__ float red[4][8][16][17];
  const int tid = threadIdx.x;
  const int w = tid >> 6, lane = tid & 63;
  const int quad = lane >> 4, l16 = lane & 15;
  const int n0 = blockIdx.x * 16;
  floatx4 acc[8] = {};
  for (int ki8 = 0; ki8 < 8; ++ki8) {
    const int k0 = (w * 8 + ki8) * 32 + quad * 8;
    const float* bp = Wxh + (size_t)(n0 + l16) * Hdim + k0;
    floatx4 b0 = *(const floatx4*)bp;
    floatx4 b1 = *(const floatx4*)(bp + 4);
    short8 bhi, blo;
    split8(b0, b1, bhi, blo);
#pragma unroll
    for (int mi = 0; mi < 8; ++mi) {
      const float* ap = embed + (size_t)(mi * 16 + l16) * Hdim + k0;
      floatx4 a0 = *(const floatx4*)ap;
      floatx4 a1 = *(const floatx4*)(ap + 4);
      short8 ahi, alo;
      split8(a0, a1, ahi, alo);
      acc[mi] = MFMA_BF16(ahi, bhi, acc[mi]);
      acc[mi] = MFMA_BF16(ahi, blo, acc[mi]);
      acc[mi] = MFMA_BF16(alo, bhi, acc[mi]);
    }
  }
#pragma unroll
  for (int mi = 0; mi < 8; ++mi)
#pragma unroll
    for (int r = 0; r < 4; ++r)
      red[w][mi][quad * 4 + r][l16] = acc[mi][r];
  __syncthreads();
  for (int i = tid; i < 8 * 16 * 16; i += 256) {
    int mi = i >> 8, rr = (i >> 4) & 15, cc = i & 15;
    float s = red[0][mi][rr][cc] + red[1][mi][rr][cc] +
              red[2][mi][rr][cc] + red[3][mi][rr][cc];
    E2[(size_t)(mi * 16 + rr) * Hdim + n0 + cc] = s;
  }
}

template <bool LOCAL>
__device__ __forceinline__ void rnn_loop(
    const int* __restrict__ xg, const float* __restrict__ fc_b,
    unsigned short* hb0, unsigned short* hb1, int* gflags, int* myflag,
    float* __restrict__ dout, short8 (&Bhi)[2][8], short8 (&Blo)[2][8],
    float (&e2s)[Vdim][NB + 1], float (&redc)[4][MB][NB + 1],
    float (&redf)[4][MB][17], unsigned short (&fcs)[VB][Hdim + 8],
    float (&bias2)[NB], int (&xi)[MB], int tid, int w, int lane, int quad,
    int l16, int r0, int n0, int v0) {
  // PACKED flags (round-6): group's 32 flags = 32 contiguous ints (2 lines).
  // Wave w's 8 producers (blocks 8w..8w+7) span 32 BYTES -> each poll is ONE
  // cache-line request instead of 8. Poll fabric traffic drops 8x (old
  // FPAD=256B layout: 1024 polling waves x 8 lines every ~150cy ~ 8+ TB/s of
  // pure IC poll spam = the congestion that masked rounds 3-5's gains).
  // Union over the 4 waves covers all 32 flags before syncA (WAR on hbuf).
  // Flags are ALWAYS IC-scope (replay-safe, prior-session proven invariant).
  const int* fp = gflags + w * 8 + (lane & 7);
  int va = 0, vb = 0;  // loop-carried: 2 pre-issued flag samples in flight

#pragma unroll 1
  for (int t = 0; t <= Sdim; ++t) {
    if (t < Sdim && tid < MB) xi[tid] = xg[(size_t)(r0 + tid) * Sdim + t];

    short8 A0[8], A1[8];  // live past the publish: deferred fc head uses them
    const bool recc = (t < Sdim);

    if (t >= 1) {
      // Pipelined poll, pre-issued at the end of iter t-1 so the first
      // sample's IC round-trip overlapped the deferred fc head + loop tail.
      // Checks use vmcnt(1) = "all but newest retired": with in-order
      // retirement, the checked (non-newest) value is always valid, however
      // many younger ops (xi load, out-store) are in flight.
      const int target = t;
      for (;;) {
        asm volatile("s_waitcnt vmcnt(1)" : "+v"(va));
        if (__all(va >= target)) break;
        __builtin_amdgcn_s_sleep(1);
        asm volatile("global_load_dword %0, %1, off sc0 sc1"
                     : "=&v"(va) : "v"(fp) : "memory");
        asm volatile("s_waitcnt vmcnt(1)" : "+v"(vb));
        if (__all(vb >= target)) break;
        __builtin_amdgcn_s_sleep(1);
        asm volatile("global_load_dword %0, %1, off sc0 sc1"
                     : "=&v"(vb) : "v"(fp) : "memory");
      }
      // Drain the <=1 stale poll load BEFORE LOADI16: vmcnt retires in
      // order, so a stale older IC load would gate every CHUNK wait behind
      // its full latency (round-3 regression, -36us).
      asm volatile("s_waitcnt vmcnt(0)" ::: "memory");
      __atomic_signal_fence(__ATOMIC_SEQ_CST);

      const unsigned short* hp = ((t - 1) & 1) ? hb1 : hb0;
      const unsigned short* p0 = hp + (size_t)(r0 + l16) * Hdim + w * 256 + quad * 8;
      const unsigned short* p1 = p0 + (size_t)16 * Hdim;
      floatx4 accr[2][2] = {};
      if (LOCAL) { LOADI16("sc0"); } else { LOADI16("sc0 sc1"); }
      CHUNK(0, 14) CHUNK(1, 12) CHUNK(2, 10) CHUNK(3, 8)
      CHUNK(4, 6)  CHUNK(5, 4)  CHUNK(6, 2)  CHUNK(7, 0)
      if (recc) {
#pragma unroll
        for (int mi = 0; mi < 2; ++mi)
#pragma unroll
          for (int ni = 0; ni < 2; ++ni)
#pragma unroll
            for (int r = 0; r < 4; ++r)
              redc[w][mi * 16 + quad * 4 + r][ni * 16 + l16] = accr[mi][ni][r];
      }
    }
    __syncthreads();  // syncA: redc ready, xi ready

    // epilogue: h_t = tanh(E2[x] + bias + h@Whh^T); 4 neurons/thread, 8B store
    if (t < Sdim) {
      unsigned short* hw = (t & 1) ? hb1 : hb0;
      const int m = tid >> 3, nl0 = (tid & 7) * 4;
      float hv[4];
      union { unsigned short us[4]; unsigned long long q; } pk;
#pragma unroll
      for (int e = 0; e < 4; ++e) {
        int nl = nl0 + e;
        float s = e2s[xi[m]][nl] + bias2[nl];
        if (t >= 1)
          s += redc[0][m][nl] + redc[1][m][nl] + redc[2][m][nl] + redc[3][m][nl];
        hv[e] = fast_tanh(s);
        pk.us[e] = f2bf(hv[e]);
      }
      unsigned short* hdst = hw + (size_t)(r0 + m) * Hdim + n0 + nl0;
      if (LOCAL)
        *(unsigned long long*)hdst = pk.q;  // write-through -> shared XCD L2
      else
        ic_store(hdst, pk.q);
      if (t == Sdim - 1) {
#pragma unroll
        for (int e = 0; e < 4; ++e)
          dout[(size_t)Bdim * Sdim * Vdim + (size_t)(r0 + m) * Hdim + n0 + nl0 + e] = hv[e];
      }
      // publish: __syncthreads drains vmcnt(0) per wave (h stores acked at
      // L2/IC) before the barrier; then one IC-scope relaxed flag store.
      // Packed line shared by 16 producers: relaxed fire-and-forget dword
      // stores to distinct dwords -- serialization happens at IC, off the
      // producer's critical path.
      __syncthreads();  // syncB
      __atomic_signal_fence(__ATOMIC_SEQ_CST);
      if (tid == 0)
        __hip_atomic_store(myflag, t + 1, __ATOMIC_RELAXED, __HIP_MEMORY_SCOPE_AGENT);
    }
    // deferred fc head + out-store: runs AFTER the publish, hidden under the
    // peers' flag-propagation/poll latency. A0/A1 still in registers.
    // redf WAR safe single-buffered: reads (post-syncC at t) are separated
    // from the next write (post-syncB at t+1) by two barriers.
    if (t >= 1) {
      floatx4 accf[2] = {};
#pragma unroll
      for (int ki = 0; ki < 8; ++ki) {
        short8 bf = *(const short8*)(&fcs[l16 & 3][w * 256 + ki * 32 + quad * 8]);
        accf[0] = MFMA_BF16(A0[ki], bf, accf[0]);
        accf[1] = MFMA_BF16(A1[ki], bf, accf[1]);
      }
#pragma unroll
      for (int mi = 0; mi < 2; ++mi)
#pragma unroll
        for (int r = 0; r < 4; ++r)
          redf[w][mi * 16 + quad * 4 + r][l16] = accf[mi][r];
      __syncthreads();  // syncC (post-publish, off the inter-block chain)
      if (tid < MB * VB) {
        int m = tid >> 2, vv = tid & 3;
        float o = redf[0][m][vv] + redf[1][m][vv] + redf[2][m][vv] + redf[3][m][vv] + fc_b[v0 + vv];
        dout[((size_t)(r0 + m) * Sdim + (t - 1)) * Vdim + v0 + vv] = o;
      }
    }
    // Pre-issue next iter's two poll samples at the very END of the body:
    // after syncC (so no barrier's vmcnt(0) stalls on them) and after the
    // out-store (older than the polls -> next check's vmcnt(1) covers it).
    if (t < Sdim) {
      asm volatile("global_load_dword %0, %2, off sc0 sc1\n\t"
                   "global_load_dword %1, %2, off sc0 sc1"
                   : "=&v"(va), "=&v"(vb) : "v"(fp) : "memory");
    }
  }
}

__global__ __launch_bounds__(256, 1) void rnn_kernel(
    const int* __restrict__ xg, const float* __restrict__ Whh,
    const float* __restrict__ Wxh_b, const float* __restrict__ Whh_b,
    const float* __restrict__ fc_w, const float* __restrict__ fc_b,
    const float* __restrict__ E2, unsigned short* __restrict__ hbuf,
    int* __restrict__ flags, int* __restrict__ xcds, float* __restrict__ dout) {
  __shared__ float e2s[Vdim][NB + 1];
  __shared__ float redc[4][MB][NB + 1];
  __shared__ float redf[4][MB][17];
  __shared__ unsigned short fcs[VB][Hdim + 8];
  __shared__ float bias2[NB];
  __shared__ int xi[MB];
  __shared__ int sh_mode;

  const int tid = threadIdx.x;
  const int w = tid >> 6, lane = tid & 63;
  const int quad = lane >> 4, l16 = lane & 15;
  const int bid = blockIdx.x;
  const int g = bid & 7, j = bid >> 3;   // FIXED grouping (round-3 proven)
  const int r0 = g * MB, n0 = j * NB, v0 = j * VB;
  // PACKED flag layout: group g's 32 flags at ints [g*GSTRIDE, g*GSTRIDE+32),
  // groups 256B apart (no cross-group line sharing).
  int* gflags = flags + g * GSTRIDE;
  int* myflag = gflags + j;

  // 1) publish my physical XCD id (IC atomics; memset-visible, replay-safe)
  if (tid == 0) {
    int xcc = (int)(__builtin_amdgcn_s_getreg((3 << 11) | 20) & 7);  // HW_REG_XCC_ID
    __hip_atomic_store(xcds + g * NBLK + j, xcc + 1, __ATOMIC_RELAXED,
                       __HIP_MEMORY_SCOPE_AGENT);
  }

  // 2) preload Whh slice as hi/lo bf16 MFMA fragments (reused 256 steps)
  short8 Bhi[2][8], Blo[2][8];
#pragma unroll
  for (int ni = 0; ni < 2; ++ni)
#pragma unroll
    for (int ki = 0; ki < 8; ++ki) {
      const int n = n0 + ni * 16 + l16;
      const int k0 = w * 256 + ki * 32 + quad * 8;
      const float* p = Whh + (size_t)n * Hdim + k0;
      floatx4 f0 = *(const floatx4*)p;
      floatx4 f1 = *(const floatx4*)(p + 4);
      split8(f0, f1, Bhi[ni][ki], Blo[ni][ki]);
    }
  for (int i = tid; i < VB * Hdim; i += 256) {
    int r = i >> 10, c = i & (Hdim - 1);
    fcs[r][c] = f2bf(fc_w[(size_t)(v0 + r) * Hdim + c]);
  }
  for (int i = tid; i < Vdim * NB; i += 256) {
    int v = i >> 5, nl = i & 31;
    e2s[v][nl] = E2[(size_t)v * Hdim + n0 + nl];
  }
  if (tid < NB) bias2[tid] = Wxh_b[n0 + tid] + Whh_b[n0 + tid];

  // 3) per-GROUP registration: poll my group's 32 xcd ids (deadlock-safe).
  //    LOCAL mode iff all 32 blocks of this group sit on one physical XCD.
  if (w == 0) {
    int v;
    for (;;) {
      v = __hip_atomic_load(xcds + g * NBLK + (lane & 31), __ATOMIC_RELAXED,
                            __HIP_MEMORY_SCOPE_AGENT);
      if (__all(v != 0)) break;
      __builtin_amdgcn_s_sleep(1);
    }
    int x0 = __shfl(v, 0);
    bool eq = __all(v == x0);
    if (lane == 0) sh_mode = eq ? 1 : 0;
  }
  __syncthreads();
  const bool local_mode = (sh_mode != 0);

  unsigned short* hb0 = hbuf;
  unsigned short* hb1 = hbuf + (size_t)Bdim * Hdim;

  if (local_mode)
    rnn_loop<true>(xg, fc_b, hb0, hb1, gflags, myflag, dout, Bhi, Blo, e2s,
                   redc, redf, fcs, bias2, xi, tid, w, lane, quad, l16, r0, n0, v0);
  else
    rnn_loop<false>(xg, fc_b, hb0, hb1, gflags, myflag, dout, Bhi, Blo, e2s,
                    redc, redf, fcs, bias2, xi, tid, w, lane, quad, l16, r0, n0, v0);
}

extern "C" void kernel_launch(void* const* d_in, const int* in_sizes, int n_in,
                              void* d_out, int out_size, void* d_ws, size_t ws_size,
                              hipStream_t stream) {
  const int* x = (const int*)d_in[0];
  const float* embed = (const float*)d_in[1];
  const float* Wxh_w = (const float*)d_in[2];
  const float* Wxh_b = (const float*)d_in[3];
  const float* Whh_w = (const float*)d_in[4];
  const float* Whh_b = (const float*)d_in[5];
  const float* fc_w = (const float*)d_in[6];
  const float* fc_b = (const float*)d_in[7];
  float* out = (float*)d_out;

  char* ws = (char*)d_ws;
  float* E2 = (float*)ws;                                   // 512 KB
  unsigned short* hbuf = (unsigned short*)(ws + 524288);    // 1 MB
  int* flags = (int*)(ws + 1572864);                        // packed: 8 x 256B
  int* xcds = (int*)(ws + 1572864 + 65536);                 // 256 ints

  hipMemsetAsync(flags, 0, 65536 + 256 * sizeof(int), stream);
  e2_kernel<<<dim3(Hdim / 16), dim3(256), 0, stream>>>(embed, Wxh_w, E2);
  rnn_kernel<<<dim3(256), dim3(256), 0, stream>>>(x, Whh_w, Wxh_b, Whh_b, fc_w,
                                                  fc_b, E2, hbuf, flags, xcds, out);
}

// Round 7
// 892.049 us; speedup vs baseline: 1.1054x; 1.1054x over previous
//
#include <hip/hip_runtime.h>
#include <hip/hip_bf16.h>

#define Bdim 256
#define Sdim 256
#define Hdim 1024
#define Vdim 128

#define NGRP 8    // batch groups
#define MB   32   // batch rows per group
#define NBLK 32   // blocks per group
#define NB   32   // neurons per block
#define VB   4    // vocab outputs per block (128/32)
#define FPAD 64   // ints per flag (256B private line per producer: r6 lesson)

typedef __attribute__((ext_vector_type(8))) short short8;
typedef __attribute__((ext_vector_type(4))) float floatx4;

#define MFMA_BF16(a, b, c) __builtin_amdgcn_mfma_f32_16x16x32_bf16((a), (b), (c), 0, 0, 0)

__device__ __forceinline__ unsigned short f2bf(float f) {
  union { float f; unsigned u; } v; v.f = f;
  unsigned r = v.u + 0x7fffu + ((v.u >> 16) & 1u);
  return (unsigned short)(r >> 16);
}
__device__ __forceinline__ float bf2f(unsigned short s) {
  union { unsigned u; float f; } v; v.u = ((unsigned)s) << 16;
  return v.f;
}
__device__ __forceinline__ void split8(floatx4 a, floatx4 b, short8& hi, short8& lo) {
#pragma unroll
  for (int e = 0; e < 4; ++e) {
    unsigned short h0 = f2bf(a[e]);
    hi[e] = (short)h0;
    lo[e] = (short)f2bf(a[e] - bf2f(h0));
    unsigned short h1 = f2bf(b[e]);
    hi[e + 4] = (short)h1;
    lo[e + 4] = (short)f2bf(b[e] - bf2f(h1));
  }
}

// tanh via native exp + rcp: abs err <1e-6 (<< bf16 h quantization 2^-9).
__device__ __forceinline__ float fast_tanh(float x) {
  float e = __expf(2.0f * x);
  return 1.0f - 2.0f * __builtin_amdgcn_rcpf(e + 1.0f);
}

// Issue 8 h-fragment loads (A[0..7]) with NO trailing waitcnt. Consumption is
// gated per-chunk by CHUNK()'s vmcnt(7-k) waits, so rec-MFMAs pipeline behind
// the L2 broadcast. PRECONDITION (round-3 lesson): vmcnt queue EMPTY at issue
// -- vmcnt retires IN ORDER; an older in-flight load would gate every wait.
#define LOADI8(SC)                                                         \
  asm volatile("global_load_dwordx4 %0, %8, off " SC "\n\t"                \
               "global_load_dwordx4 %1, %8, off offset:64 " SC "\n\t"      \
               "global_load_dwordx4 %2, %8, off offset:128 " SC "\n\t"     \
               "global_load_dwordx4 %3, %8, off offset:192 " SC "\n\t"     \
               "global_load_dwordx4 %4, %8, off offset:256 " SC "\n\t"     \
               "global_load_dwordx4 %5, %8, off offset:320 " SC "\n\t"     \
               "global_load_dwordx4 %6, %8, off offset:384 " SC "\n\t"     \
               "global_load_dwordx4 %7, %8, off offset:448 " SC "\n\t"     \
               : "=&v"(A[0]), "=&v"(A[1]), "=&v"(A[2]), "=&v"(A[3]),       \
                 "=&v"(A[4]), "=&v"(A[5]), "=&v"(A[6]), "=&v"(A[7])        \
               : "v"(p0)                                                   \
               : "memory")

// Wait for chunk K. Clean queue at LOADI8 => <=7-K outstanding means A[K]
// retired. "+v" tie = data dep so MFMAs can't hoist (rule #18). hi,hi,lo,lo
// order gives 1-MFMA gap between same-accumulator ops; the partner wave on
// the SIMD (2 waves/SIMD now) fills remaining latency.
#define CHUNK(K, VM)                                                         \
  asm volatile("s_waitcnt vmcnt(" #VM ")" : "+v"(A[K]));                     \
  if (recc) {                                                                \
    accr[0] = MFMA_BF16(A[K], Bhi[0][K], accr[0]);                           \
    accr[1] = MFMA_BF16(A[K], Bhi[1][K], accr[1]);                           \
    accr[0] = MFMA_BF16(A[K], Blo[0][K], accr[0]);                           \
    accr[1] = MFMA_BF16(A[K], Blo[1][K], accr[1]);                           \
  }

// E2[v][k] = sum_h embed[v][h] * Wxh[k][h]   (128 x 1024), near-fp32 via hi/lo
__global__ __launch_bounds__(256) void e2_kernel(const float* __restrict__ embed,
                                                 const float* __restrict__ Wxh,
                                                 float* __restrict__ E2) {
  __shared__ float red[4][8][16][17];
  const int tid = threadIdx.x;
  const int w = tid >> 6, lane = tid & 63;
  const int quad = lane >> 4, l16 = lane & 15;
  const int n0 = blockIdx.x * 16;
  floatx4 acc[8] = {};
  for (int ki8 = 0; ki8 < 8; ++ki8) {
    const int k0 = (w * 8 + ki8) * 32 + quad * 8;
    const float* bp = Wxh + (size_t)(n0 + l16) * Hdim + k0;
    floatx4 b0 = *(const floatx4*)bp;
    floatx4 b1 = *(const floatx4*)(bp + 4);
    short8 bhi, blo;
    split8(b0, b1, bhi, blo);
#pragma unroll
    for (int mi = 0; mi < 8; ++mi) {
      const float* ap = embed + (size_t)(mi * 16 + l16) * Hdim + k0;
      floatx4 a0 = *(const floatx4*)ap;
      floatx4 a1 = *(const floatx4*)(ap + 4);
      short8 ahi, alo;
      split8(a0, a1, ahi, alo);
      acc[mi] = MFMA_BF16(ahi, bhi, acc[mi]);
      acc[mi] = MFMA_BF16(ahi, blo, acc[mi]);
      acc[mi] = MFMA_BF16(alo, bhi, acc[mi]);
    }
  }
#pragma unroll
  for (int mi = 0; mi < 8; ++mi)
#pragma unroll
    for (int r = 0; r < 4; ++r)
      red[w][mi][quad * 4 + r][l16] = acc[mi][r];
  __syncthreads();
  for (int i = tid; i < 8 * 16 * 16; i += 256) {
    int mi = i >> 8, rr = (i >> 4) & 15, cc = i & 15;
    float s = red[0][mi][rr][cc] + red[1][mi][rr][cc] +
              red[2][mi][rr][cc] + red[3][mi][rr][cc];
    E2[(size_t)(mi * 16 + rr) * Hdim + n0 + cc] = s;
  }
}

template <bool LOCAL>
__device__ __forceinline__ void rnn_loop(
    const int* __restrict__ xg, const float* __restrict__ fc_b,
    unsigned short* hb0, unsigned short* hb1, int* gflags, int* myflag,
    float* __restrict__ dout, short8 (&Bhi)[2][8], short8 (&Blo)[2][8],
    float (&e2s)[Vdim][NB + 1], float (&redc)[4][MB][NB + 1],
    float (&redf)[4][MB][17], unsigned short (&fcs)[VB][Hdim + 8],
    float (&bias2)[NB], int (&xi)[MB], int tid, int w, int lane, int quad,
    int l16, int r0, int n0, int v0) {
  // 8-wave split: wave w = (rh, kh): rows rh*16..+16, K-quarter kh*256..+256.
  // 2 waves/SIMD -> two independent CHUNK/MFMA pipelines interleave on each
  // SIMD, hiding MFMA dependent-issue latency and L2 load latency (round-7
  // theory: MfmaUtil 15% @ 1 wave/SIMD = latency-inflated 3x).
  const int rh = w >> 2, kh = w & 3;
  // Wave (rh,kh) consumes h cols [kh*256, kh*256+256) <- produced by blocks
  // j = kh*8..kh*8+7 -> poll those 8 flags (each replicated over 8 lanes).
  // Union over kh=0..3 covers all 32 flags before syncA (WAR on hbuf).
  // Flags ALWAYS IC-scope on private 256B lines (r6: packed lines delay the
  // producer store behind reader traffic; prior session: IC is replay-safe).
  const int* fp = gflags + (kh * 8 + (lane & 7)) * FPAD;
  int va = 0, vb = 0;  // loop-carried: 2 pre-issued flag samples in flight

#pragma unroll 1
  for (int t = 0; t <= Sdim; ++t) {
    if (t < Sdim && tid < MB) xi[tid] = xg[(size_t)(r0 + tid) * Sdim + t];

    short8 A[8];  // live past the publish: deferred fc head uses them
    const bool recc = (t < Sdim);

    if (t >= 1) {
      // Pipelined poll, pre-issued at the end of iter t-1. Checks use
      // vmcnt(1) = "all but newest retired": in-order retirement => the
      // checked (non-newest) value is always a completed fresh sample.
      const int target = t;
      for (;;) {
        asm volatile("s_waitcnt vmcnt(1)" : "+v"(va));
        if (__all(va >= target)) break;
        __builtin_amdgcn_s_sleep(1);
        asm volatile("global_load_dword %0, %1, off sc0 sc1"
                     : "=&v"(va) : "v"(fp) : "memory");
        asm volatile("s_waitcnt vmcnt(1)" : "+v"(vb));
        if (__all(vb >= target)) break;
        __builtin_amdgcn_s_sleep(1);
        asm volatile("global_load_dword %0, %1, off sc0 sc1"
                     : "=&v"(vb) : "v"(fp) : "memory");
      }
      // Drain the <=1 stale poll load BEFORE LOADI8 (round-3 lesson).
      asm volatile("s_waitcnt vmcnt(0)" ::: "memory");
      __atomic_signal_fence(__ATOMIC_SEQ_CST);

      const unsigned short* hp = ((t - 1) & 1) ? hb1 : hb0;
      const unsigned short* p0 =
          hp + (size_t)(r0 + rh * 16 + l16) * Hdim + kh * 256 + quad * 8;
      floatx4 accr[2] = {};
      if (LOCAL) { LOADI8("sc0"); } else { LOADI8("sc0 sc1"); }
      CHUNK(0, 7) CHUNK(1, 6) CHUNK(2, 5) CHUNK(3, 4)
      CHUNK(4, 3) CHUNK(5, 2) CHUNK(6, 1) CHUNK(7, 0)
      if (recc) {
#pragma unroll
        for (int ni = 0; ni < 2; ++ni)
#pragma unroll
          for (int r = 0; r < 4; ++r)
            redc[kh][rh * 16 + quad * 4 + r][ni * 16 + l16] = accr[ni][r];
      }
    }
    __syncthreads();  // syncA: redc ready, xi ready

    // epilogue: h_t = tanh(E2[x] + bias + h@Whh^T); 2 neurons/thread (512 th)
    if (t < Sdim) {
      unsigned short* hw = (t & 1) ? hb1 : hb0;
      const int m = tid >> 4, nl0 = (tid & 15) * 2;
      float hv[2];
      union { unsigned short us[2]; unsigned u; } pk;
#pragma unroll
      for (int e = 0; e < 2; ++e) {
        int nl = nl0 + e;
        float s = e2s[xi[m]][nl] + bias2[nl];
        if (t >= 1)
          s += redc[0][m][nl] + redc[1][m][nl] + redc[2][m][nl] + redc[3][m][nl];
        hv[e] = fast_tanh(s);
        pk.us[e] = f2bf(hv[e]);
      }
      unsigned short* hdst = hw + (size_t)(r0 + m) * Hdim + n0 + nl0;
      if (LOCAL)
        *(unsigned*)hdst = pk.u;  // write-back L2, XCD-shared
      else
        __hip_atomic_store((unsigned*)hdst, pk.u, __ATOMIC_RELAXED,
                           __HIP_MEMORY_SCOPE_AGENT);
      if (t == Sdim - 1) {
#pragma unroll
        for (int e = 0; e < 2; ++e)
          dout[(size_t)Bdim * Sdim * Vdim + (size_t)(r0 + m) * Hdim + n0 + nl0 + e] = hv[e];
      }
      // publish: __syncthreads drains vmcnt(0) per wave (h stores acked at
      // L2/IC) before the barrier; then one IC-scope relaxed flag store.
      __syncthreads();  // syncB
      __atomic_signal_fence(__ATOMIC_SEQ_CST);
      if (tid == 0)
        __hip_atomic_store(myflag, t + 1, __ATOMIC_RELAXED, __HIP_MEMORY_SCOPE_AGENT);
    }
    // deferred fc head + out-store: AFTER the publish, hidden under peers'
    // poll latency. A still in registers. redf WAR safe: reads (post-syncC
    // at t) separated from next write (post-syncB at t+1) by two barriers.
    if (t >= 1) {
      floatx4 accf = {};
#pragma unroll
      for (int ki = 0; ki < 8; ++ki) {
        short8 bf = *(const short8*)(&fcs[l16 & 3][kh * 256 + ki * 32 + quad * 8]);
        accf = MFMA_BF16(A[ki], bf, accf);
      }
#pragma unroll
      for (int r = 0; r < 4; ++r)
        redf[kh][rh * 16 + quad * 4 + r][l16] = accf[r];
      __syncthreads();  // syncC (post-publish, off the inter-block chain)
      if (tid < MB * VB) {
        int m = tid >> 2, vv = tid & 3;
        float o = redf[0][m][vv] + redf[1][m][vv] + redf[2][m][vv] + redf[3][m][vv] + fc_b[v0 + vv];
        dout[((size_t)(r0 + m) * Sdim + (t - 1)) * Vdim + v0 + vv] = o;
      }
    }
    // Pre-issue next iter's two poll samples at the very END of the body
    // (after syncC so no barrier drains them; out-store is older so the
    // next vmcnt(1) check still covers both poll loads).
    if (t < Sdim) {
      asm volatile("global_load_dword %0, %2, off sc0 sc1\n\t"
                   "global_load_dword %1, %2, off sc0 sc1"
                   : "=&v"(va), "=&v"(vb) : "v"(fp) : "memory");
    }
  }
}

__global__ __launch_bounds__(512, 2) void rnn_kernel(
    const int* __restrict__ xg, const float* __restrict__ Whh,
    const float* __restrict__ Wxh_b, const float* __restrict__ Whh_b,
    const float* __restrict__ fc_w, const float* __restrict__ fc_b,
    const float* __restrict__ E2, unsigned short* __restrict__ hbuf,
    int* __restrict__ flags, int* __restrict__ xcds, float* __restrict__ dout) {
  __shared__ float e2s[Vdim][NB + 1];
  __shared__ float redc[4][MB][NB + 1];
  __shared__ float redf[4][MB][17];
  __shared__ unsigned short fcs[VB][Hdim + 8];
  __shared__ float bias2[NB];
  __shared__ int xi[MB];
  __shared__ int sh_mode;

  const int tid = threadIdx.x;
  const int w = tid >> 6, lane = tid & 63;
  const int quad = lane >> 4, l16 = lane & 15;
  const int bid = blockIdx.x;
  const int g = bid & 7, j = bid >> 3;   // FIXED grouping (prior-session proven)
  const int r0 = g * MB, n0 = j * NB, v0 = j * VB;
  int* gflags = flags + g * NBLK * FPAD;
  int* myflag = gflags + j * FPAD;

  // 1) publish my physical XCD id (IC atomics; memset-visible, replay-safe)
  if (tid == 0) {
    int xcc = (int)(__builtin_amdgcn_s_getreg((3 << 11) | 20) & 7);  // HW_REG_XCC_ID
    __hip_atomic_store(xcds + g * NBLK + j, xcc + 1, __ATOMIC_RELAXED,
                       __HIP_MEMORY_SCOPE_AGENT);
  }

  // 2) preload Whh slice as hi/lo bf16 MFMA fragments (reused 256 steps).
  //    Wave (rh,kh) holds neurons n0..n0+32 x K-quarter kh*256..+256.
  //    (rh=0 and rh=1 waves hold identical copies -- register space allows.)
  const int kh = w & 3;
  short8 Bhi[2][8], Blo[2][8];
#pragma unroll
  for (int ni = 0; ni < 2; ++ni)
#pragma unroll
    for (int ki = 0; ki < 8; ++ki) {
      const int n = n0 + ni * 16 + l16;
      const int k0 = kh * 256 + ki * 32 + quad * 8;
      const float* p = Whh + (size_t)n * Hdim + k0;
      floatx4 f0 = *(const floatx4*)p;
      floatx4 f1 = *(const floatx4*)(p + 4);
      split8(f0, f1, Bhi[ni][ki], Blo[ni][ki]);
    }
  for (int i = tid; i < VB * Hdim; i += 512) {
    int r = i >> 10, c = i & (Hdim - 1);
    fcs[r][c] = f2bf(fc_w[(size_t)(v0 + r) * Hdim + c]);
  }
  for (int i = tid; i < Vdim * NB; i += 512) {
    int v = i >> 5, nl = i & 31;
    e2s[v][nl] = E2[(size_t)v * Hdim + n0 + nl];
  }
  if (tid < NB) bias2[tid] = Wxh_b[n0 + tid] + Whh_b[n0 + tid];

  // 3) per-GROUP registration: poll my group's 32 xcd ids (deadlock-safe).
  //    LOCAL mode iff all 32 blocks of this group sit on one physical XCD.
  if (w == 0) {
    int v;
    for (;;) {
      v = __hip_atomic_load(xcds + g * NBLK + (lane & 31), __ATOMIC_RELAXED,
                            __HIP_MEMORY_SCOPE_AGENT);
      if (__all(v != 0)) break;
      __builtin_amdgcn_s_sleep(1);
    }
    int x0 = __shfl(v, 0);
    bool eq = __all(v == x0);
    if (lane == 0) sh_mode = eq ? 1 : 0;
  }
  __syncthreads();
  const bool local_mode = (sh_mode != 0);

  unsigned short* hb0 = hbuf;
  unsigned short* hb1 = hbuf + (size_t)Bdim * Hdim;

  if (local_mode)
    rnn_loop<true>(xg, fc_b, hb0, hb1, gflags, myflag, dout, Bhi, Blo, e2s,
                   redc, redf, fcs, bias2, xi, tid, w, lane, quad, l16, r0, n0, v0);
  else
    rnn_loop<false>(xg, fc_b, hb0, hb1, gflags, myflag, dout, Bhi, Blo, e2s,
                    redc, redf, fcs, bias2, xi, tid, w, lane, quad, l16, r0, n0, v0);
}

extern "C" void kernel_launch(void* const* d_in, const int* in_sizes, int n_in,
                              void* d_out, int out_size, void* d_ws, size_t ws_size,
                              hipStream_t stream) {
  const int* x = (const int*)d_in[0];
  const float* embed = (const float*)d_in[1];
  const float* Wxh_w = (const float*)d_in[2];
  const float* Wxh_b = (const float*)d_in[3];
  const float* Whh_w = (const float*)d_in[4];
  const float* Whh_b = (const float*)d_in[5];
  const float* fc_w = (const float*)d_in[6];
  const float* fc_b = (const float*)d_in[7];
  float* out = (float*)d_out;

  char* ws = (char*)d_ws;
  float* E2 = (float*)ws;                                   // 512 KB
  unsigned short* hbuf = (unsigned short*)(ws + 524288);    // 1 MB
  int* flags = (int*)(ws + 1572864);                        // 256 x 256B = 64 KB
  int* xcds = (int*)(ws + 1572864 + 65536);                 // 256 ints

  hipMemsetAsync(flags, 0, 256 * FPAD * sizeof(int) + 256 * sizeof(int), stream);
  e2_kernel<<<dim3(Hdim / 16), dim3(256), 0, stream>>>(embed, Wxh_w, E2);
  rnn_kernel<<<dim3(256), dim3(512), 0, stream>>>(x, Whh_w, Wxh_b, Whh_b, fc_w,
                                                  fc_b, E2, hbuf, flags, xcds, out);
}

// Round 8
// 886.396 us; speedup vs baseline: 1.1125x; 1.0064x over previous
//
#include <hip/hip_runtime.h>
#include <hip/hip_bf16.h>

#define Bdim 256
#define Sdim 256
#define Hdim 1024
#define Vdim 128

#define NGRP 8    // batch groups
#define MB   32   // batch rows per group
#define NBLK 32   // blocks per group
#define NB   32   // neurons per block
#define VB   4    // vocab outputs per block (128/32)
#define FPAD 64   // ints per flag (256B private line per producer: r6 lesson)

typedef __attribute__((ext_vector_type(8))) short short8;
typedef __attribute__((ext_vector_type(4))) float floatx4;

#define MFMA_BF16(a, b, c) __builtin_amdgcn_mfma_f32_16x16x32_bf16((a), (b), (c), 0, 0, 0)

__device__ __forceinline__ unsigned short f2bf(float f) {
  union { float f; unsigned u; } v; v.f = f;
  unsigned r = v.u + 0x7fffu + ((v.u >> 16) & 1u);
  return (unsigned short)(r >> 16);
}
__device__ __forceinline__ float bf2f(unsigned short s) {
  union { unsigned u; float f; } v; v.u = ((unsigned)s) << 16;
  return v.f;
}
__device__ __forceinline__ void split8(floatx4 a, floatx4 b, short8& hi, short8& lo) {
#pragma unroll
  for (int e = 0; e < 4; ++e) {
    unsigned short h0 = f2bf(a[e]);
    hi[e] = (short)h0;
    lo[e] = (short)f2bf(a[e] - bf2f(h0));
    unsigned short h1 = f2bf(b[e]);
    hi[e + 4] = (short)h1;
    lo[e + 4] = (short)f2bf(b[e] - bf2f(h1));
  }
}

// tanh via native exp + rcp: abs err <1e-6 (<< bf16 h quantization 2^-9).
__device__ __forceinline__ float fast_tanh(float x) {
  float e = __expf(2.0f * x);
  return 1.0f - 2.0f * __builtin_amdgcn_rcpf(e + 1.0f);
}

// Issue 8 h-fragment loads (A[0..7]) with NO trailing waitcnt. Consumption is
// gated per-chunk by CHUNK()'s vmcnt(7-k) waits, so rec-MFMAs pipeline behind
// the L2 broadcast. PRECONDITION (round-3 lesson): vmcnt queue EMPTY at issue
// -- vmcnt retires IN ORDER; an older in-flight load would gate every wait.
#define LOADI8(SC)                                                         \
  asm volatile("global_load_dwordx4 %0, %8, off " SC "\n\t"                \
               "global_load_dwordx4 %1, %8, off offset:64 " SC "\n\t"      \
               "global_load_dwordx4 %2, %8, off offset:128 " SC "\n\t"     \
               "global_load_dwordx4 %3, %8, off offset:192 " SC "\n\t"     \
               "global_load_dwordx4 %4, %8, off offset:256 " SC "\n\t"     \
               "global_load_dwordx4 %5, %8, off offset:320 " SC "\n\t"     \
               "global_load_dwordx4 %6, %8, off offset:384 " SC "\n\t"     \
               "global_load_dwordx4 %7, %8, off offset:448 " SC "\n\t"     \
               : "=&v"(A[0]), "=&v"(A[1]), "=&v"(A[2]), "=&v"(A[3]),       \
                 "=&v"(A[4]), "=&v"(A[5]), "=&v"(A[6]), "=&v"(A[7])        \
               : "v"(p0)                                                   \
               : "memory")

// Wait for chunk K. Clean queue at LOADI8 => <=7-K outstanding means A[K]
// retired. "+v" tie = data dep so MFMAs can't hoist (rule #18).
#define CHUNK(K, VM)                                                         \
  asm volatile("s_waitcnt vmcnt(" #VM ")" : "+v"(A[K]));                     \
  if (recc) {                                                                \
    accr[0] = MFMA_BF16(A[K], Bhi[0][K], accr[0]);                           \
    accr[1] = MFMA_BF16(A[K], Bhi[1][K], accr[1]);                           \
    accr[0] = MFMA_BF16(A[K], Blo[0][K], accr[0]);                           \
    accr[1] = MFMA_BF16(A[K], Blo[1][K], accr[1]);                           \
  }

// E2[v][k] = sum_h embed[v][h] * Wxh[k][h]   (128 x 1024), near-fp32 via hi/lo
__global__ __launch_bounds__(256) void e2_kernel(const float* __restrict__ embed,
                                                 const float* __restrict__ Wxh,
                                                 float* __restrict__ E2) {
  __shared__ float red[4][8][16][17];
  const int tid = threadIdx.x;
  const int w = tid >> 6, lane = tid & 63;
  const int quad = lane >> 4, l16 = lane & 15;
  const int n0 = blockIdx.x * 16;
  floatx4 acc[8] = {};
  for (int ki8 = 0; ki8 < 8; ++ki8) {
    const int k0 = (w * 8 + ki8) * 32 + quad * 8;
    const float* bp = Wxh + (size_t)(n0 + l16) * Hdim + k0;
    floatx4 b0 = *(const floatx4*)bp;
    floatx4 b1 = *(const floatx4*)(bp + 4);
    short8 bhi, blo;
    split8(b0, b1, bhi, blo);
#pragma unroll
    for (int mi = 0; mi < 8; ++mi) {
      const float* ap = embed + (size_t)(mi * 16 + l16) * Hdim + k0;
      floatx4 a0 = *(const floatx4*)ap;
      floatx4 a1 = *(const floatx4*)(ap + 4);
      short8 ahi, alo;
      split8(a0, a1, ahi, alo);
      acc[mi] = MFMA_BF16(ahi, bhi, acc[mi]);
      acc[mi] = MFMA_BF16(ahi, blo, acc[mi]);
      acc[mi] = MFMA_BF16(alo, bhi, acc[mi]);
    }
  }
#pragma unroll
  for (int mi = 0; mi < 8; ++mi)
#pragma unroll
    for (int r = 0; r < 4; ++r)
      red[w][mi][quad * 4 + r][l16] = acc[mi][r];
  __syncthreads();
  for (int i = tid; i < 8 * 16 * 16; i += 256) {
    int mi = i >> 8, rr = (i >> 4) & 15, cc = i & 15;
    float s = red[0][mi][rr][cc] + red[1][mi][rr][cc] +
              red[2][mi][rr][cc] + red[3][mi][rr][cc];
    E2[(size_t)(mi * 16 + rr) * Hdim + n0 + cc] = s;
  }
}

template <bool LOCAL>
__device__ __forceinline__ void rnn_loop(
    const float* __restrict__ fc_b, unsigned short* hb0, unsigned short* hb1,
    int* gflags, int* myflag, float* __restrict__ dout,
    short8 (&Bhi)[2][8], short8 (&Blo)[2][8],
    float (&e2s)[Vdim][NB + 1], float (&redc)[4][MB][NB + 1],
    float (&redf)[4][MB][17], unsigned short (&fcs)[VB][Hdim + 8],
    float (&bias2)[NB], int (&xi_lds)[Sdim][33], float (&outbuf)[8][128],
    int tid, int w, int lane, int quad, int l16, int r0, int n0, int v0) {
  // 8-wave split: wave w = (rh, kh): rows rh*16..+16, K-quarter kh*256..+256.
  const int rh = w >> 2, kh = w & 3;
  // Wave (rh,kh) consumes h cols [kh*256, kh*256+256) <- produced by blocks
  // j = kh*8..kh*8+7 -> poll those 8 flags (each replicated over 8 lanes).
  // Union over kh=0..3 covers all 32 flags before syncA (WAR on hbuf).
  // Flags ALWAYS IC-scope on private 256B lines (r6 lesson; replay-safe).
  const int* fp = gflags + (kh * 8 + (lane & 7)) * FPAD;
  int va = 0, vb = 0;  // loop-carried: 2 pre-issued flag samples in flight

  // r8: wave 0's vmcnt path is CLEAN in steady state -- no xi load (LDS
  // preloaded), no per-step out-store (8-step batch). The flag-publishing
  // wave no longer serializes on HBM latency each step.

#pragma unroll 1
  for (int t = 0; t <= Sdim; ++t) {
    short8 A[8];  // live past the publish: deferred fc head uses them
    const bool recc = (t < Sdim);

    if (t >= 1) {
      // Pipelined poll, pre-issued at the end of iter t-1. Checks use
      // vmcnt(1) = "all but newest retired": in-order retirement => the
      // checked (non-newest) value is always a completed fresh sample.
      const int target = t;
      for (;;) {
        asm volatile("s_waitcnt vmcnt(1)" : "+v"(va));
        if (__all(va >= target)) break;
        __builtin_amdgcn_s_sleep(1);
        asm volatile("global_load_dword %0, %1, off sc0 sc1"
                     : "=&v"(va) : "v"(fp) : "memory");
        asm volatile("s_waitcnt vmcnt(1)" : "+v"(vb));
        if (__all(vb >= target)) break;
        __builtin_amdgcn_s_sleep(1);
        asm volatile("global_load_dword %0, %1, off sc0 sc1"
                     : "=&v"(vb) : "v"(fp) : "memory");
      }
      // Drain the <=1 stale poll load BEFORE LOADI8 (round-3 lesson).
      asm volatile("s_waitcnt vmcnt(0)" ::: "memory");
      __atomic_signal_fence(__ATOMIC_SEQ_CST);

      const unsigned short* hp = ((t - 1) & 1) ? hb1 : hb0;
      const unsigned short* p0 =
          hp + (size_t)(r0 + rh * 16 + l16) * Hdim + kh * 256 + quad * 8;
      floatx4 accr[2] = {};
      if (LOCAL) { LOADI8("sc0"); } else { LOADI8("sc0 sc1"); }
      CHUNK(0, 7) CHUNK(1, 6) CHUNK(2, 5) CHUNK(3, 4)
      CHUNK(4, 3) CHUNK(5, 2) CHUNK(6, 1) CHUNK(7, 0)
      if (recc) {
#pragma unroll
        for (int ni = 0; ni < 2; ++ni)
#pragma unroll
          for (int r = 0; r < 4; ++r)
            redc[kh][rh * 16 + quad * 4 + r][ni * 16 + l16] = accr[ni][r];
      }
    }
    __syncthreads();  // syncA: redc ready

    // epilogue: h_t = tanh(E2[x] + bias + h@Whh^T); 2 neurons/thread (512 th)
    if (t < Sdim) {
      unsigned short* hw = (t & 1) ? hb1 : hb0;
      const int m = tid >> 4, nl0 = (tid & 15) * 2;
      const int xv = xi_lds[t][m];  // preloaded: no HBM access in the loop
      float hv[2];
      union { unsigned short us[2]; unsigned u; } pk;
#pragma unroll
      for (int e = 0; e < 2; ++e) {
        int nl = nl0 + e;
        float s = e2s[xv][nl] + bias2[nl];
        if (t >= 1)
          s += redc[0][m][nl] + redc[1][m][nl] + redc[2][m][nl] + redc[3][m][nl];
        hv[e] = fast_tanh(s);
        pk.us[e] = f2bf(hv[e]);
      }
      unsigned short* hdst = hw + (size_t)(r0 + m) * Hdim + n0 + nl0;
      if (LOCAL)
        *(unsigned*)hdst = pk.u;  // write-back L2, XCD-shared
      else
        __hip_atomic_store((unsigned*)hdst, pk.u, __ATOMIC_RELAXED,
                           __HIP_MEMORY_SCOPE_AGENT);
      if (t == Sdim - 1) {
#pragma unroll
        for (int e = 0; e < 2; ++e)
          dout[(size_t)Bdim * Sdim * Vdim + (size_t)(r0 + m) * Hdim + n0 + nl0 + e] = hv[e];
      }
      // publish: __syncthreads drains vmcnt(0) per wave (h stores acked at
      // L2/IC) before the barrier; then one IC-scope relaxed flag store.
      __syncthreads();  // syncB
      __atomic_signal_fence(__ATOMIC_SEQ_CST);
      if (tid == 0)
        __hip_atomic_store(myflag, t + 1, __ATOMIC_RELAXED, __HIP_MEMORY_SCOPE_AGENT);
    }
    // deferred fc head: AFTER the publish, hidden under peers' poll latency.
    // A still in registers. redf WAR safe: reads (post-syncC at t) separated
    // from next write (post-syncB at t+1) by two barriers.
    if (t >= 1) {
      floatx4 accf = {};
#pragma unroll
      for (int ki = 0; ki < 8; ++ki) {
        short8 bf = *(const short8*)(&fcs[l16 & 3][kh * 256 + ki * 32 + quad * 8]);
        accf = MFMA_BF16(A[ki], bf, accf);
      }
#pragma unroll
      for (int r = 0; r < 4; ++r)
        redf[kh][rh * 16 + quad * 4 + r][l16] = accf[r];
      __syncthreads();  // syncC (post-publish, off the inter-block chain)
      // out row t-1 -> LDS batch buffer (no per-step HBM store: its ack
      // would gate the next poll's vmcnt check -- the r8 discovery).
      if (tid < MB * VB) {
        int m = tid >> 2, vv = tid & 3;
        float o = redf[0][m][vv] + redf[1][m][vv] + redf[2][m][vv] + redf[3][m][vv] + fc_b[v0 + vv];
        outbuf[(t - 1) & 7][tid] = o;
        // flush every 8th row; each thread reads back only its OWN slots
        // (outbuf[k][tid]) -> no barrier needed. Store-ack cost amortized 8x.
        if (((t - 1) & 7) == 7) {
          const int tb = t - 8;
#pragma unroll
          for (int k = 0; k < 8; ++k)
            dout[((size_t)(r0 + m) * Sdim + (tb + k)) * Vdim + v0 + vv] = outbuf[k][tid];
        }
      }
    }
    // Pre-issue next iter's two poll samples at the very END of the body
    // (younger than any flush stores -> those are waited once per 8 steps).
    if (t < Sdim) {
      asm volatile("global_load_dword %0, %2, off sc0 sc1\n\t"
                   "global_load_dword %1, %2, off sc0 sc1"
                   : "=&v"(va), "=&v"(vb) : "v"(fp) : "memory");
    }
  }
}

__global__ __launch_bounds__(512, 2) void rnn_kernel(
    const int* __restrict__ xg, const float* __restrict__ Whh,
    const float* __restrict__ Wxh_b, const float* __restrict__ Whh_b,
    const float* __restrict__ fc_w, const float* __restrict__ fc_b,
    const float* __restrict__ E2, unsigned short* __restrict__ hbuf,
    int* __restrict__ flags, int* __restrict__ xcds, float* __restrict__ dout) {
  __shared__ float e2s[Vdim][NB + 1];
  __shared__ float redc[4][MB][NB + 1];
  __shared__ float redf[4][MB][17];
  __shared__ unsigned short fcs[VB][Hdim + 8];
  __shared__ float bias2[NB];
  __shared__ int xi_lds[Sdim][33];   // all timesteps' indices (33: bank pad)
  __shared__ float outbuf[8][128];   // 8-step out batch
  __shared__ int sh_mode;

  const int tid = threadIdx.x;
  const int w = tid >> 6, lane = tid & 63;
  const int quad = lane >> 4, l16 = lane & 15;
  const int bid = blockIdx.x;
  const int g = bid & 7, j = bid >> 3;   // FIXED grouping (prior-session proven)
  const int r0 = g * MB, n0 = j * NB, v0 = j * VB;
  int* gflags = flags + g * NBLK * FPAD;
  int* myflag = gflags + j * FPAD;

  // 1) publish my physical XCD id (IC atomics; memset-visible, replay-safe)
  if (tid == 0) {
    int xcc = (int)(__builtin_amdgcn_s_getreg((3 << 11) | 20) & 7);  // HW_REG_XCC_ID
    __hip_atomic_store(xcds + g * NBLK + j, xcc + 1, __ATOMIC_RELAXED,
                       __HIP_MEMORY_SCOPE_AGENT);
  }

  // 2) preload Whh slice as hi/lo bf16 MFMA fragments (reused 256 steps).
  const int kh = w & 3;
  short8 Bhi[2][8], Blo[2][8];
#pragma unroll
  for (int ni = 0; ni < 2; ++ni)
#pragma unroll
    for (int ki = 0; ki < 8; ++ki) {
      const int n = n0 + ni * 16 + l16;
      const int k0 = kh * 256 + ki * 32 + quad * 8;
      const float* p = Whh + (size_t)n * Hdim + k0;
      floatx4 f0 = *(const floatx4*)p;
      floatx4 f1 = *(const floatx4*)(p + 4);
      split8(f0, f1, Bhi[ni][ki], Blo[ni][ki]);
    }
  for (int i = tid; i < VB * Hdim; i += 512) {
    int r = i >> 10, c = i & (Hdim - 1);
    fcs[r][c] = f2bf(fc_w[(size_t)(v0 + r) * Hdim + c]);
  }
  for (int i = tid; i < Vdim * NB; i += 512) {
    int v = i >> 5, nl = i & 31;
    e2s[v][nl] = E2[(size_t)v * Hdim + n0 + nl];
  }
  if (tid < NB) bias2[tid] = Wxh_b[n0 + tid] + Whh_b[n0 + tid];
  // preload ALL xi for the group's 32 rows (32 KB): removes the per-step
  // HBM index load from the loop (it sat on wave 0's vmcnt drain path).
  for (int i = tid; i < MB * Sdim; i += 512) {
    int m = i >> 8, tt = i & 255;   // coalesced global read, padded LDS write
    xi_lds[tt][m] = xg[(size_t)(r0 + m) * Sdim + tt];
  }

  // 3) per-GROUP registration: poll my group's 32 xcd ids (deadlock-safe).
  //    LOCAL mode iff all 32 blocks of this group sit on one physical XCD.
  if (w == 0) {
    int v;
    for (;;) {
      v = __hip_atomic_load(xcds + g * NBLK + (lane & 31), __ATOMIC_RELAXED,
                            __HIP_MEMORY_SCOPE_AGENT);
      if (__all(v != 0)) break;
      __builtin_amdgcn_s_sleep(1);
    }
    int x0 = __shfl(v, 0);
    bool eq = __all(v == x0);
    if (lane == 0) sh_mode = eq ? 1 : 0;
  }
  __syncthreads();
  const bool local_mode = (sh_mode != 0);

  unsigned short* hb0 = hbuf;
  unsigned short* hb1 = hbuf + (size_t)Bdim * Hdim;

  if (local_mode)
    rnn_loop<true>(fc_b, hb0, hb1, gflags, myflag, dout, Bhi, Blo, e2s,
                   redc, redf, fcs, bias2, xi_lds, outbuf, tid, w, lane, quad,
                   l16, r0, n0, v0);
  else
    rnn_loop<false>(fc_b, hb0, hb1, gflags, myflag, dout, Bhi, Blo, e2s,
                    redc, redf, fcs, bias2, xi_lds, outbuf, tid, w, lane, quad,
                    l16, r0, n0, v0);
}

extern "C" void kernel_launch(void* const* d_in, const int* in_sizes, int n_in,
                              void* d_out, int out_size, void* d_ws, size_t ws_size,
                              hipStream_t stream) {
  const int* x = (const int*)d_in[0];
  const float* embed = (const float*)d_in[1];
  const float* Wxh_w = (const float*)d_in[2];
  const float* Wxh_b = (const float*)d_in[3];
  const float* Whh_w = (const float*)d_in[4];
  const float* Whh_b = (const float*)d_in[5];
  const float* fc_w = (const float*)d_in[6];
  const float* fc_b = (const float*)d_in[7];
  float* out = (float*)d_out;

  char* ws = (char*)d_ws;
  float* E2 = (float*)ws;                                   // 512 KB
  unsigned short* hbuf = (unsigned short*)(ws + 524288);    // 1 MB
  int* flags = (int*)(ws + 1572864);                        // 256 x 256B = 64 KB
  int* xcds = (int*)(ws + 1572864 + 65536);                 // 256 ints

  hipMemsetAsync(flags, 0, 256 * FPAD * sizeof(int) + 256 * sizeof(int), stream);
  e2_kernel<<<dim3(Hdim / 16), dim3(256), 0, stream>>>(embed, Wxh_w, E2);
  rnn_kernel<<<dim3(256), dim3(512), 0, stream>>>(x, Whh_w, Wxh_b, Whh_b, fc_w,
                                                  fc_b, E2, hbuf, flags, xcds, out);
}

// Round 9
// 668.175 us; speedup vs baseline: 1.4758x; 1.3266x over previous
//
#include <hip/hip_runtime.h>
#include <hip/hip_bf16.h>

#define Bdim 256
#define Sdim 256
#define Hdim 1024
#define Vdim 128

#define NGRP 16   // batch groups (16 rows each)
#define MB   16   // batch rows per group
#define NBLK 16   // blocks per group
#define NB   64   // neurons per block
#define VB   8    // vocab outputs per block (128/16)
#define FPAD 64   // ints per flag (256B private line per producer: r6 lesson)

typedef __attribute__((ext_vector_type(8))) short short8;
typedef __attribute__((ext_vector_type(4))) float floatx4;

#define MFMA_BF16(a, b, c) __builtin_amdgcn_mfma_f32_16x16x32_bf16((a), (b), (c), 0, 0, 0)

__device__ __forceinline__ unsigned short f2bf(float f) {
  union { float f; unsigned u; } v; v.f = f;
  unsigned r = v.u + 0x7fffu + ((v.u >> 16) & 1u);
  return (unsigned short)(r >> 16);
}
__device__ __forceinline__ float bf2f(unsigned short s) {
  union { unsigned u; float f; } v; v.u = ((unsigned)s) << 16;
  return v.f;
}
__device__ __forceinline__ void split8(floatx4 a, floatx4 b, short8& hi, short8& lo) {
#pragma unroll
  for (int e = 0; e < 4; ++e) {
    unsigned short h0 = f2bf(a[e]);
    hi[e] = (short)h0;
    lo[e] = (short)f2bf(a[e] - bf2f(h0));
    unsigned short h1 = f2bf(b[e]);
    hi[e + 4] = (short)h1;
    lo[e + 4] = (short)f2bf(b[e] - bf2f(h1));
  }
}

// tanh via native exp + rcp: abs err <1e-6 (<< bf16 h quantization 2^-9).
__device__ __forceinline__ float fast_tanh(float x) {
  float e = __expf(2.0f * x);
  return 1.0f - 2.0f * __builtin_amdgcn_rcpf(e + 1.0f);
}

// Issue 4 h-fragment loads (A[0..3], 32KB/block total across waves) with NO
// trailing waitcnt; CHUNK()'s vmcnt(3-k) gates consumption so rec-MFMAs
// pipeline behind the L2 broadcast. PRECONDITION (round-3 lesson): vmcnt
// queue EMPTY at issue -- vmcnt retires IN ORDER.
#define LOADI4(SC)                                                         \
  asm volatile("global_load_dwordx4 %0, %4, off " SC "\n\t"                \
               "global_load_dwordx4 %1, %4, off offset:64 " SC "\n\t"      \
               "global_load_dwordx4 %2, %4, off offset:128 " SC "\n\t"     \
               "global_load_dwordx4 %3, %4, off offset:192 " SC "\n\t"     \
               : "=&v"(A[0]), "=&v"(A[1]), "=&v"(A[2]), "=&v"(A[3])        \
               : "v"(p0)                                                   \
               : "memory")

// Wait for chunk K. Clean queue at LOADI4 => <=3-K outstanding means A[K]
// retired. "+v" tie = data dep so MFMAs can't hoist (rule #18). hi-round
// then lo-round: dep distance 4 between same-accumulator MFMAs.
#define CHUNK(K, VM)                                                         \
  asm volatile("s_waitcnt vmcnt(" #VM ")" : "+v"(A[K]));                     \
  if (recc) {                                                                \
    accr[0] = MFMA_BF16(A[K], Bhi[0][K], accr[0]);                           \
    accr[1] = MFMA_BF16(A[K], Bhi[1][K], accr[1]);                           \
    accr[2] = MFMA_BF16(A[K], Bhi[2][K], accr[2]);                           \
    accr[3] = MFMA_BF16(A[K], Bhi[3][K], accr[3]);                           \
    accr[0] = MFMA_BF16(A[K], Blo[0][K], accr[0]);                           \
    accr[1] = MFMA_BF16(A[K], Blo[1][K], accr[1]);                           \
    accr[2] = MFMA_BF16(A[K], Blo[2][K], accr[2]);                           \
    accr[3] = MFMA_BF16(A[K], Blo[3][K], accr[3]);                           \
  }

// E2[v][k] = sum_h embed[v][h] * Wxh[k][h]   (128 x 1024), near-fp32 via hi/lo
__global__ __launch_bounds__(256) void e2_kernel(const float* __restrict__ embed,
                                                 const float* __restrict__ Wxh,
                                                 float* __restrict__ E2) {
  __shared__ float red[4][8][16][17];
  const int tid = threadIdx.x;
  const int w = tid >> 6, lane = tid & 63;
  const int quad = lane >> 4, l16 = lane & 15;
  const int n0 = blockIdx.x * 16;
  floatx4 acc[8] = {};
  for (int ki8 = 0; ki8 < 8; ++ki8) {
    const int k0 = (w * 8 + ki8) * 32 + quad * 8;
    const float* bp = Wxh + (size_t)(n0 + l16) * Hdim + k0;
    floatx4 b0 = *(const floatx4*)bp;
    floatx4 b1 = *(const floatx4*)(bp + 4);
    short8 bhi, blo;
    split8(b0, b1, bhi, blo);
#pragma unroll
    for (int mi = 0; mi < 8; ++mi) {
      const float* ap = embed + (size_t)(mi * 16 + l16) * Hdim + k0;
      floatx4 a0 = *(const floatx4*)ap;
      floatx4 a1 = *(const floatx4*)(ap + 4);
      short8 ahi, alo;
      split8(a0, a1, ahi, alo);
      acc[mi] = MFMA_BF16(ahi, bhi, acc[mi]);
      acc[mi] = MFMA_BF16(ahi, blo, acc[mi]);
      acc[mi] = MFMA_BF16(alo, bhi, acc[mi]);
    }
  }
#pragma unroll
  for (int mi = 0; mi < 8; ++mi)
#pragma unroll
    for (int r = 0; r < 4; ++r)
      red[w][mi][quad * 4 + r][l16] = acc[mi][r];
  __syncthreads();
  for (int i = tid; i < 8 * 16 * 16; i += 256) {
    int mi = i >> 8, rr = (i >> 4) & 15, cc = i & 15;
    float s = red[0][mi][rr][cc] + red[1][mi][rr][cc] +
              red[2][mi][rr][cc] + red[3][mi][rr][cc];
    E2[(size_t)(mi * 16 + rr) * Hdim + n0 + cc] = s;
  }
}

template <bool LOCAL>
__device__ __forceinline__ void rnn_loop(
    const float* __restrict__ fc_b, unsigned short* hb0, unsigned short* hb1,
    int* gflags, int* myflag, float* __restrict__ dout,
    short8 (&Bhi)[4][4], short8 (&Blo)[4][4],
    float (&e2s)[Vdim][NB + 1], float (&redc)[8][MB][68],
    float (&redf)[8][MB][20], unsigned short (&fcs)[VB][Hdim + 8],
    float (&bias2)[NB], int (&xi_lds)[Sdim][MB + 1], float (&outbuf)[8][128],
    int tid, int w, int lane, int quad, int l16, int r0, int n0, int v0) {
  // r9 re-tile: 16 groups x 16 rows; 16 blocks/group x 64 neurons. Wave w
  // owns k-eighth [w*128, w*128+128) for all 16 rows x 64 neurons.
  // Its k-slice is produced by exactly blocks j = 2w, 2w+1 -> poll 2 flags.
  // Union over 8 waves covers all 16 flags before syncA (WAR on hbuf).
  // Flags ALWAYS IC-scope on private 256B lines (r6 lesson; replay-safe).
  const int* fp = gflags + (2 * w + (lane & 1)) * FPAD;
  int va = 0, vb = 0;  // loop-carried: 2 pre-issued flag samples in flight

#pragma unroll 1
  for (int t = 0; t <= Sdim; ++t) {
    short8 A[4];  // live past the publish: deferred fc head uses them
    const bool recc = (t < Sdim);

    if (t >= 1) {
      // Pipelined poll, pre-issued at the end of iter t-1. Checks use
      // vmcnt(1) = "all but newest retired".
      const int target = t;
      for (;;) {
        asm volatile("s_waitcnt vmcnt(1)" : "+v"(va));
        if (__all(va >= target)) break;
        __builtin_amdgcn_s_sleep(1);
        asm volatile("global_load_dword %0, %1, off sc0 sc1"
                     : "=&v"(va) : "v"(fp) : "memory");
        asm volatile("s_waitcnt vmcnt(1)" : "+v"(vb));
        if (__all(vb >= target)) break;
        __builtin_amdgcn_s_sleep(1);
        asm volatile("global_load_dword %0, %1, off sc0 sc1"
                     : "=&v"(vb) : "v"(fp) : "memory");
      }
      // Drain the <=1 stale poll load BEFORE LOADI4 (round-3 lesson).
      asm volatile("s_waitcnt vmcnt(0)" ::: "memory");
      __atomic_signal_fence(__ATOMIC_SEQ_CST);

      const unsigned short* hp = ((t - 1) & 1) ? hb1 : hb0;
      const unsigned short* p0 =
          hp + (size_t)(r0 + l16) * Hdim + w * 128 + quad * 8;
      floatx4 accr[4] = {};
      if (LOCAL) { LOADI4("sc0"); } else { LOADI4("sc0 sc1"); }
      CHUNK(0, 3) CHUNK(1, 2) CHUNK(2, 1) CHUNK(3, 0)
      if (recc) {
#pragma unroll
        for (int ni = 0; ni < 4; ++ni)
#pragma unroll
          for (int r = 0; r < 4; ++r)
            redc[w][quad * 4 + r][ni * 16 + l16] = accr[ni][r];
      }
    }
    __syncthreads();  // syncA: redc ready

    // epilogue: h_t = tanh(E2[x] + bias + h@Whh^T); 2 neurons/thread (512 th)
    if (t < Sdim) {
      unsigned short* hw = (t & 1) ? hb1 : hb0;
      const int m = tid >> 5, nl0 = (tid & 31) * 2;
      const int xv = xi_lds[t][m];  // preloaded: no HBM access in the loop
      float2 s2 = *(const float2*)&e2s[xv][nl0];
      {
        float2 b2 = *(const float2*)&bias2[nl0];
        s2.x += b2.x; s2.y += b2.y;
      }
      if (t >= 1) {
#pragma unroll
        for (int kh = 0; kh < 8; ++kh) {
          float2 rc = *(const float2*)&redc[kh][m][nl0];
          s2.x += rc.x; s2.y += rc.y;
        }
      }
      float hv0 = fast_tanh(s2.x), hv1 = fast_tanh(s2.y);
      union { unsigned short us[2]; unsigned u; } pk;
      pk.us[0] = f2bf(hv0); pk.us[1] = f2bf(hv1);
      unsigned short* hdst = hw + (size_t)(r0 + m) * Hdim + n0 + nl0;
      if (LOCAL)
        *(unsigned*)hdst = pk.u;  // write-back L2, XCD-shared
      else
        __hip_atomic_store((unsigned*)hdst, pk.u, __ATOMIC_RELAXED,
                           __HIP_MEMORY_SCOPE_AGENT);
      if (t == Sdim - 1) {
        dout[(size_t)Bdim * Sdim * Vdim + (size_t)(r0 + m) * Hdim + n0 + nl0] = hv0;
        dout[(size_t)Bdim * Sdim * Vdim + (size_t)(r0 + m) * Hdim + n0 + nl0 + 1] = hv1;
      }
      // publish: __syncthreads drains vmcnt(0) per wave (h stores acked at
      // L2/IC) before the barrier; then one IC-scope relaxed flag store.
      __syncthreads();  // syncB
      __atomic_signal_fence(__ATOMIC_SEQ_CST);
      if (tid == 0)
        __hip_atomic_store(myflag, t + 1, __ATOMIC_RELAXED, __HIP_MEMORY_SCOPE_AGENT);
    }
    // deferred fc head: AFTER the publish, hidden under peers' poll latency.
    // A still in registers. redf WAR safe: reads (post-syncC at t) separated
    // from next write (post-syncB at t+1) by two barriers.
    if (t >= 1) {
      floatx4 accf = {};
#pragma unroll
      for (int kc = 0; kc < 4; ++kc) {
        short8 bf = *(const short8*)(&fcs[l16 & 7][w * 128 + kc * 32 + quad * 8]);
        accf = MFMA_BF16(A[kc], bf, accf);
      }
#pragma unroll
      for (int r = 0; r < 4; ++r)
        redf[w][quad * 4 + r][l16] = accf[r];
      __syncthreads();  // syncC (post-publish, off the inter-block chain)
      // out row t-1 -> LDS batch buffer; flush every 8th step (r8: per-step
      // HBM store acks would gate the next poll's vmcnt check).
      if (tid < MB * VB) {
        int m = tid >> 3, vv = tid & 7;
        float o = fc_b[v0 + vv];
#pragma unroll
        for (int kh = 0; kh < 8; ++kh) o += redf[kh][m][vv];
        outbuf[(t - 1) & 7][tid] = o;
        if (((t - 1) & 7) == 7) {
          const int tb = t - 8;
#pragma unroll
          for (int k = 0; k < 8; ++k)
            dout[((size_t)(r0 + m) * Sdim + (tb + k)) * Vdim + v0 + vv] = outbuf[k][tid];
        }
      }
    }
    // Pre-issue next iter's two poll samples at the very END of the body.
    if (t < Sdim) {
      asm volatile("global_load_dword %0, %2, off sc0 sc1\n\t"
                   "global_load_dword %1, %2, off sc0 sc1"
                   : "=&v"(va), "=&v"(vb) : "v"(fp) : "memory");
    }
  }
}

__global__ __launch_bounds__(512, 2) void rnn_kernel(
    const int* __restrict__ xg, const float* __restrict__ Whh,
    const float* __restrict__ Wxh_b, const float* __restrict__ Whh_b,
    const float* __restrict__ fc_w, const float* __restrict__ fc_b,
    const float* __restrict__ E2, unsigned short* __restrict__ hbuf,
    int* __restrict__ flags, int* __restrict__ xcds, float* __restrict__ dout) {
  __shared__ float e2s[Vdim][NB + 1];          // 33.3 KB
  __shared__ float redc[8][MB][68];            // 34.8 KB (stride 68 = 4 mod 8
                                               //  -> 2-way-only bank aliasing)
  __shared__ float redf[8][MB][20];            // 10.2 KB (stride 20 = 4 mod 8)
  __shared__ unsigned short fcs[VB][Hdim + 8]; // 16.5 KB
  __shared__ float bias2[NB];
  __shared__ int xi_lds[Sdim][MB + 1];         // 17.4 KB
  __shared__ float outbuf[8][128];             // 4 KB
  __shared__ int sh_mode;

  const int tid = threadIdx.x;
  const int w = tid >> 6, lane = tid & 63;
  const int quad = lane >> 4, l16 = lane & 15;
  const int bid = blockIdx.x;
  // r9 grouping: g = bid & 15 -> bid%8 = g%8 => whole group on ONE XCD
  // (2 groups per XCD), preserving the proven XCD-alignment premise.
  const int g = bid & 15, j = bid >> 4;
  const int r0 = g * MB, n0 = j * NB, v0 = j * VB;
  int* gflags = flags + g * NBLK * FPAD;
  int* myflag = gflags + j * FPAD;

  // 1) publish my physical XCD id (IC atomics; memset-visible, replay-safe)
  if (tid == 0) {
    int xcc = (int)(__builtin_amdgcn_s_getreg((3 << 11) | 20) & 7);  // HW_REG_XCC_ID
    __hip_atomic_store(xcds + g * NBLK + j, xcc + 1, __ATOMIC_RELAXED,
                       __HIP_MEMORY_SCOPE_AGENT);
  }

  // 2) preload Whh slice as hi/lo bf16 MFMA fragments (reused 256 steps).
  //    Wave w holds neurons n0..n0+64 x k-eighth [w*128, w*128+128).
  short8 Bhi[4][4], Blo[4][4];
#pragma unroll
  for (int ni = 0; ni < 4; ++ni)
#pragma unroll
    for (int kc = 0; kc < 4; ++kc) {
      const int n = n0 + ni * 16 + l16;
      const int k0 = w * 128 + kc * 32 + quad * 8;
      const float* p = Whh + (size_t)n * Hdim + k0;
      floatx4 f0 = *(const floatx4*)p;
      floatx4 f1 = *(const floatx4*)(p + 4);
      split8(f0, f1, Bhi[ni][kc], Blo[ni][kc]);
    }
  for (int i = tid; i < VB * Hdim; i += 512) {
    int r = i >> 10, c = i & (Hdim - 1);
    fcs[r][c] = f2bf(fc_w[(size_t)(v0 + r) * Hdim + c]);
  }
  for (int i = tid; i < Vdim * NB; i += 512) {
    int v = i >> 6, nl = i & 63;
    e2s[v][nl] = E2[(size_t)v * Hdim + n0 + nl];
  }
  if (tid < NB) bias2[tid] = Wxh_b[n0 + tid] + Whh_b[n0 + tid];
  // preload ALL xi for the group's 16 rows (16 KB): no HBM index loads in
  // the loop (r8: they sat on wave 0's vmcnt drain path).
  for (int i = tid; i < MB * Sdim; i += 512) {
    int m = i >> 8, tt = i & 255;
    xi_lds[tt][m] = xg[(size_t)(r0 + m) * Sdim + tt];
  }

  // 3) per-GROUP registration: poll my group's 16 xcd ids (deadlock-safe).
  //    LOCAL mode iff all 16 blocks of this group sit on one physical XCD.
  if (w == 0) {
    int v;
    for (;;) {
      v = __hip_atomic_load(xcds + g * NBLK + (lane & 15), __ATOMIC_RELAXED,
                            __HIP_MEMORY_SCOPE_AGENT);
      if (__all(v != 0)) break;
      __builtin_amdgcn_s_sleep(1);
    }
    int x0 = __shfl(v, 0);
    bool eq = __all(v == x0);
    if (lane == 0) sh_mode = eq ? 1 : 0;
  }
  __syncthreads();
  const bool local_mode = (sh_mode != 0);

  unsigned short* hb0 = hbuf;
  unsigned short* hb1 = hbuf + (size_t)Bdim * Hdim;

  if (local_mode)
    rnn_loop<true>(fc_b, hb0, hb1, gflags, myflag, dout, Bhi, Blo, e2s,
                   redc, redf, fcs, bias2, xi_lds, outbuf, tid, w, lane, quad,
                   l16, r0, n0, v0);
  else
    rnn_loop<false>(fc_b, hb0, hb1, gflags, myflag, dout, Bhi, Blo, e2s,
                    redc, redf, fcs, bias2, xi_lds, outbuf, tid, w, lane, quad,
                    l16, r0, n0, v0);
}

extern "C" void kernel_launch(void* const* d_in, const int* in_sizes, int n_in,
                              void* d_out, int out_size, void* d_ws, size_t ws_size,
                              hipStream_t stream) {
  const int* x = (const int*)d_in[0];
  const float* embed = (const float*)d_in[1];
  const float* Wxh_w = (const float*)d_in[2];
  const float* Wxh_b = (const float*)d_in[3];
  const float* Whh_w = (const float*)d_in[4];
  const float* Whh_b = (const float*)d_in[5];
  const float* fc_w = (const float*)d_in[6];
  const float* fc_b = (const float*)d_in[7];
  float* out = (float*)d_out;

  char* ws = (char*)d_ws;
  float* E2 = (float*)ws;                                   // 512 KB
  unsigned short* hbuf = (unsigned short*)(ws + 524288);    // 1 MB
  int* flags = (int*)(ws + 1572864);                        // 256 x 256B = 64 KB
  int* xcds = (int*)(ws + 1572864 + 65536);                 // 256 ints

  hipMemsetAsync(flags, 0, 256 * FPAD * sizeof(int) + 256 * sizeof(int), stream);
  e2_kernel<<<dim3(Hdim / 16), dim3(256), 0, stream>>>(embed, Wxh_w, E2);
  rnn_kernel<<<dim3(256), dim3(512), 0, stream>>>(x, Whh_w, Wxh_b, Whh_b, fc_w,
                                                  fc_b, E2, hbuf, flags, xcds, out);
}

// Round 12
// 666.953 us; speedup vs baseline: 1.4785x; 1.0018x over previous
//
#include <hip/hip_runtime.h>
#include <hip/hip_bf16.h>

#define Bdim 256
#define Sdim 256
#define Hdim 1024
#define Vdim 128

#define NGRP 16   // batch groups (16 rows each)
#define MB   16   // batch rows per group
#define NBLK 16   // blocks per group
#define NB   64   // neurons per block
#define VB   8    // vocab outputs per block (128/16)
#define FPAD 64   // ints per flag (256B private line per producer: r6 lesson)

typedef __attribute__((ext_vector_type(8))) short short8;
typedef __attribute__((ext_vector_type(4))) float floatx4;

#define MFMA_BF16(a, b, c) __builtin_amdgcn_mfma_f32_16x16x32_bf16((a), (b), (c), 0, 0, 0)

__device__ __forceinline__ unsigned short f2bf(float f) {
  union { float f; unsigned u; } v; v.f = f;
  unsigned r = v.u + 0x7fffu + ((v.u >> 16) & 1u);
  return (unsigned short)(r >> 16);
}
__device__ __forceinline__ float bf2f(unsigned short s) {
  union { unsigned u; float f; } v; v.u = ((unsigned)s) << 16;
  return v.f;
}
__device__ __forceinline__ void split8(floatx4 a, floatx4 b, short8& hi, short8& lo) {
#pragma unroll
  for (int e = 0; e < 4; ++e) {
    unsigned short h0 = f2bf(a[e]);
    hi[e] = (short)h0;
    lo[e] = (short)f2bf(a[e] - bf2f(h0));
    unsigned short h1 = f2bf(b[e]);
    hi[e + 4] = (short)h1;
    lo[e + 4] = (short)f2bf(b[e] - bf2f(h1));
  }
}

// tanh via native exp + rcp: abs err <1e-6 (<< bf16 h quantization 2^-9).
__device__ __forceinline__ float fast_tanh(float x) {
  float e = __expf(2.0f * x);
  return 1.0f - 2.0f * __builtin_amdgcn_rcpf(e + 1.0f);
}

// Issue 4 h-fragment loads (A[0..3], 32KB/block total across waves) with NO
// trailing waitcnt; CHUNK()'s vmcnt(3-k) gates consumption so rec-MFMAs
// pipeline behind the L2 broadcast. PRECONDITION (round-3 lesson): vmcnt
// queue EMPTY at issue -- vmcnt retires IN ORDER.
#define LOADI4(SC)                                                         \
  asm volatile("global_load_dwordx4 %0, %4, off " SC "\n\t"                \
               "global_load_dwordx4 %1, %4, off offset:64 " SC "\n\t"      \
               "global_load_dwordx4 %2, %4, off offset:128 " SC "\n\t"     \
               "global_load_dwordx4 %3, %4, off offset:192 " SC "\n\t"     \
               : "=&v"(A[0]), "=&v"(A[1]), "=&v"(A[2]), "=&v"(A[3])        \
               : "v"(p0)                                                   \
               : "memory")

// Wait for chunk K. Clean queue at LOADI4 => <=3-K outstanding means A[K]
// retired. "+v" tie = data dep so MFMAs can't hoist (rule #18). hi-round
// then lo-round: dep distance 4 between same-accumulator MFMAs.
#define CHUNK(K, VM)                                                         \
  asm volatile("s_waitcnt vmcnt(" #VM ")" : "+v"(A[K]));                     \
  if (recc) {                                                                \
    accr[0] = MFMA_BF16(A[K], Bhi[0][K], accr[0]);                           \
    accr[1] = MFMA_BF16(A[K], Bhi[1][K], accr[1]);                           \
    accr[2] = MFMA_BF16(A[K], Bhi[2][K], accr[2]);                           \
    accr[3] = MFMA_BF16(A[K], Bhi[3][K], accr[3]);                           \
    accr[0] = MFMA_BF16(A[K], Blo[0][K], accr[0]);                           \
    accr[1] = MFMA_BF16(A[K], Blo[1][K], accr[1]);                           \
    accr[2] = MFMA_BF16(A[K], Blo[2][K], accr[2]);                           \
    accr[3] = MFMA_BF16(A[K], Blo[3][K], accr[3]);                           \
  }

// E2[v][k] = sum_h embed[v][h] * Wxh[k][h]   (128 x 1024), near-fp32 via hi/lo
__global__ __launch_bounds__(256) void e2_kernel(const float* __restrict__ embed,
                                                 const float* __restrict__ Wxh,
                                                 float* __restrict__ E2) {
  __shared__ float red[4][8][16][17];
  const int tid = threadIdx.x;
  const int w = tid >> 6, lane = tid & 63;
  const int quad = lane >> 4, l16 = lane & 15;
  const int n0 = blockIdx.x * 16;
  floatx4 acc[8] = {};
  for (int ki8 = 0; ki8 < 8; ++ki8) {
    const int k0 = (w * 8 + ki8) * 32 + quad * 8;
    const float* bp = Wxh + (size_t)(n0 + l16) * Hdim + k0;
    floatx4 b0 = *(const floatx4*)bp;
    floatx4 b1 = *(const floatx4*)(bp + 4);
    short8 bhi, blo;
    split8(b0, b1, bhi, blo);
#pragma unroll
    for (int mi = 0; mi < 8; ++mi) {
      const float* ap = embed + (size_t)(mi * 16 + l16) * Hdim + k0;
      floatx4 a0 = *(const floatx4*)ap;
      floatx4 a1 = *(const floatx4*)(ap + 4);
      short8 ahi, alo;
      split8(a0, a1, ahi, alo);
      acc[mi] = MFMA_BF16(ahi, bhi, acc[mi]);
      acc[mi] = MFMA_BF16(ahi, blo, acc[mi]);
      acc[mi] = MFMA_BF16(alo, bhi, acc[mi]);
    }
  }
#pragma unroll
  for (int mi = 0; mi < 8; ++mi)
#pragma unroll
    for (int r = 0; r < 4; ++r)
      red[w][mi][quad * 4 + r][l16] = acc[mi][r];
  __syncthreads();
  for (int i = tid; i < 8 * 16 * 16; i += 256) {
    int mi = i >> 8, rr = (i >> 4) & 15, cc = i & 15;
    float s = red[0][mi][rr][cc] + red[1][mi][rr][cc] +
              red[2][mi][rr][cc] + red[3][mi][rr][cc];
    E2[(size_t)(mi * 16 + rr) * Hdim + n0 + cc] = s;
  }
}

template <bool LOCAL>
__device__ __forceinline__ void rnn_loop(
    const float* __restrict__ fc_b, unsigned short* hb0, unsigned short* hb1,
    int* gflags, int* myflag, float* __restrict__ dout,
    short8 (&Bhi)[4][4], short8 (&Blo)[4][4],
    float (&e2s)[Vdim][NB + 1], float (&redc)[8][MB][68],
    float (&redf)[8][MB][20], unsigned short (&fcs)[VB][Hdim + 8],
    float (&bias2)[NB], int (&xi_lds)[Sdim][MB + 1], float (&outbuf)[8][128],
    int tid, int w, int lane, int quad, int l16, int r0, int n0, int v0) {
  // r9 re-tile: 16 groups x 16 rows; 16 blocks/group x 64 neurons. Wave w
  // owns k-eighth [w*128, w*128+128) for all 16 rows x 64 neurons.
  // Its k-slice is produced by exactly blocks j = 2w, 2w+1 -> poll 2 flags.
  // Union over 8 waves covers all 16 flags before syncA (WAR on hbuf).
  // Flags ALWAYS IC-scope on private 256B lines. Session-hardened invariant:
  // sc0/L2-scope flag polling is empirically toxic on this platform
  // (3/3 opaque container failures: r1, r10, r11) -- do NOT retry it.
  const int* fp = gflags + (2 * w + (lane & 1)) * FPAD;
  int va = 0, vb = 0;  // loop-carried: 2 pre-issued flag samples in flight

#pragma unroll 1
  for (int t = 0; t <= Sdim; ++t) {
    short8 A[4];  // live past the publish: deferred fc head uses them
    const bool recc = (t < Sdim);

    if (t >= 1) {
      // Pipelined poll, pre-issued at the end of iter t-1. Checks use
      // vmcnt(1) = "all but newest retired".
      const int target = t;
      for (;;) {
        asm volatile("s_waitcnt vmcnt(1)" : "+v"(va));
        if (__all(va >= target)) break;
        __builtin_amdgcn_s_sleep(1);
        asm volatile("global_load_dword %0, %1, off sc0 sc1"
                     : "=&v"(va) : "v"(fp) : "memory");
        asm volatile("s_waitcnt vmcnt(1)" : "+v"(vb));
        if (__all(vb >= target)) break;
        __builtin_amdgcn_s_sleep(1);
        asm volatile("global_load_dword %0, %1, off sc0 sc1"
                     : "=&v"(vb) : "v"(fp) : "memory");
      }
      // Drain the <=1 stale poll load BEFORE LOADI4 (round-3 lesson).
      asm volatile("s_waitcnt vmcnt(0)" ::: "memory");
      __atomic_signal_fence(__ATOMIC_SEQ_CST);

      const unsigned short* hp = ((t - 1) & 1) ? hb1 : hb0;
      const unsigned short* p0 =
          hp + (size_t)(r0 + l16) * Hdim + w * 128 + quad * 8;
      floatx4 accr[4] = {};
      if (LOCAL) { LOADI4("sc0"); } else { LOADI4("sc0 sc1"); }
      CHUNK(0, 3) CHUNK(1, 2) CHUNK(2, 1) CHUNK(3, 0)
      if (recc) {
#pragma unroll
        for (int ni = 0; ni < 4; ++ni)
#pragma unroll
          for (int r = 0; r < 4; ++r)
            redc[w][quad * 4 + r][ni * 16 + l16] = accr[ni][r];
      }
    }
    __syncthreads();  // syncA: redc ready

    // epilogue: h_t = tanh(E2[x] + bias + h@Whh^T); 2 neurons/thread (512 th)
    if (t < Sdim) {
      unsigned short* hw = (t & 1) ? hb1 : hb0;
      const int m = tid >> 5, nl0 = (tid & 31) * 2;
      const int xv = xi_lds[t][m];  // preloaded: no HBM access in the loop
      float2 s2 = *(const float2*)&e2s[xv][nl0];
      {
        float2 b2 = *(const float2*)&bias2[nl0];
        s2.x += b2.x; s2.y += b2.y;
      }
      if (t >= 1) {
#pragma unroll
        for (int kh = 0; kh < 8; ++kh) {
          float2 rc = *(const float2*)&redc[kh][m][nl0];
          s2.x += rc.x; s2.y += rc.y;
        }
      }
      float hv0 = fast_tanh(s2.x), hv1 = fast_tanh(s2.y);
      union { unsigned short us[2]; unsigned u; } pk;
      pk.us[0] = f2bf(hv0); pk.us[1] = f2bf(hv1);
      unsigned short* hdst = hw + (size_t)(r0 + m) * Hdim + n0 + nl0;
      if (LOCAL)
        *(unsigned*)hdst = pk.u;  // write-back L2, XCD-shared
      else
        __hip_atomic_store((unsigned*)hdst, pk.u, __ATOMIC_RELAXED,
                           __HIP_MEMORY_SCOPE_AGENT);
      if (t == Sdim - 1) {
        dout[(size_t)Bdim * Sdim * Vdim + (size_t)(r0 + m) * Hdim + n0 + nl0] = hv0;
        dout[(size_t)Bdim * Sdim * Vdim + (size_t)(r0 + m) * Hdim + n0 + nl0 + 1] = hv1;
      }
      // publish: __syncthreads drains vmcnt(0) per wave (h stores acked at
      // L2/IC) before the barrier; then one IC-scope relaxed flag store.
      __syncthreads();  // syncB
      __atomic_signal_fence(__ATOMIC_SEQ_CST);
      if (tid == 0)
        __hip_atomic_store(myflag, t + 1, __ATOMIC_RELAXED, __HIP_MEMORY_SCOPE_AGENT);
    }
    // deferred fc head: AFTER the publish, hidden under peers' poll latency.
    // A still in registers. redf WAR safe: reads (post-syncC at t) separated
    // from next write (post-syncB at t+1) by two barriers.
    if (t >= 1) {
      floatx4 accf = {};
#pragma unroll
      for (int kc = 0; kc < 4; ++kc) {
        short8 bf = *(const short8*)(&fcs[l16 & 7][w * 128 + kc * 32 + quad * 8]);
        accf = MFMA_BF16(A[kc], bf, accf);
      }
#pragma unroll
      for (int r = 0; r < 4; ++r)
        redf[w][quad * 4 + r][l16] = accf[r];
      __syncthreads();  // syncC (post-publish, off the inter-block chain)
      // out row t-1 -> LDS batch buffer; flush every 8th step (r8: per-step
      // HBM store acks would gate the next poll's vmcnt check).
      if (tid < MB * VB) {
        int m = tid >> 3, vv = tid & 7;
        float o = fc_b[v0 + vv];
#pragma unroll
        for (int kh = 0; kh < 8; ++kh) o += redf[kh][m][vv];
        outbuf[(t - 1) & 7][tid] = o;
        if (((t - 1) & 7) == 7) {
          const int tb = t - 8;
#pragma unroll
          for (int k = 0; k < 8; ++k)
            dout[((size_t)(r0 + m) * Sdim + (tb + k)) * Vdim + v0 + vv] = outbuf[k][tid];
        }
      }
    }
    // Pre-issue next iter's two poll samples at the very END of the body.
    if (t < Sdim) {
      asm volatile("global_load_dword %0, %2, off sc0 sc1\n\t"
                   "global_load_dword %1, %2, off sc0 sc1"
                   : "=&v"(va), "=&v"(vb) : "v"(fp) : "memory");
    }
  }
}

__global__ __launch_bounds__(512, 2) void rnn_kernel(
    const int* __restrict__ xg, const float* __restrict__ Whh,
    const float* __restrict__ Wxh_b, const float* __restrict__ Whh_b,
    const float* __restrict__ fc_w, const float* __restrict__ fc_b,
    const float* __restrict__ E2, unsigned short* __restrict__ hbuf,
    int* __restrict__ flags, int* __restrict__ xcds, float* __restrict__ dout) {
  __shared__ float e2s[Vdim][NB + 1];          // 33.3 KB
  __shared__ float redc[8][MB][68];            // 34.8 KB (stride 68 = 4 mod 8
                                               //  -> 2-way-only bank aliasing)
  __shared__ float redf[8][MB][20];            // 10.2 KB (stride 20 = 4 mod 8)
  __shared__ unsigned short fcs[VB][Hdim + 8]; // 16.5 KB
  __shared__ float bias2[NB];
  __shared__ int xi_lds[Sdim][MB + 1];         // 17.4 KB
  __shared__ float outbuf[8][128];             // 4 KB
  __shared__ int sh_mode;

  const int tid = threadIdx.x;
  const int w = tid >> 6, lane = tid & 63;
  const int quad = lane >> 4, l16 = lane & 15;
  const int bid = blockIdx.x;
  // r9 grouping: g = bid & 15 -> bid%8 = g%8 => whole group on ONE XCD
  // (2 groups per XCD), preserving the proven XCD-alignment premise.
  const int g = bid & 15, j = bid >> 4;
  const int r0 = g * MB, n0 = j * NB, v0 = j * VB;
  int* gflags = flags + g * NBLK * FPAD;
  int* myflag = gflags + j * FPAD;

  // 1) publish my physical XCD id (IC atomics; memset-visible, replay-safe)
  if (tid == 0) {
    int xcc = (int)(__builtin_amdgcn_s_getreg((3 << 11) | 20) & 7);  // HW_REG_XCC_ID
    __hip_atomic_store(xcds + g * NBLK + j, xcc + 1, __ATOMIC_RELAXED,
                       __HIP_MEMORY_SCOPE_AGENT);
  }

  // 2) preload Whh slice as hi/lo bf16 MFMA fragments (reused 256 steps).
  //    Wave w holds neurons n0..n0+64 x k-eighth [w*128, w*128+128).
  short8 Bhi[4][4], Blo[4][4];
#pragma unroll
  for (int ni = 0; ni < 4; ++ni)
#pragma unroll
    for (int kc = 0; kc < 4; ++kc) {
      const int n = n0 + ni * 16 + l16;
      const int k0 = w * 128 + kc * 32 + quad * 8;
      const float* p = Whh + (size_t)n * Hdim + k0;
      floatx4 f0 = *(const floatx4*)p;
      floatx4 f1 = *(const floatx4*)(p + 4);
      split8(f0, f1, Bhi[ni][kc], Blo[ni][kc]);
    }
  for (int i = tid; i < VB * Hdim; i += 512) {
    int r = i >> 10, c = i & (Hdim - 1);
    fcs[r][c] = f2bf(fc_w[(size_t)(v0 + r) * Hdim + c]);
  }
  for (int i = tid; i < Vdim * NB; i += 512) {
    int v = i >> 6, nl = i & 63;
    e2s[v][nl] = E2[(size_t)v * Hdim + n0 + nl];
  }
  if (tid < NB) bias2[tid] = Wxh_b[n0 + tid] + Whh_b[n0 + tid];
  // preload ALL xi for the group's 16 rows (16 KB): no HBM index loads in
  // the loop (r8: they sat on wave 0's vmcnt drain path).
  for (int i = tid; i < MB * Sdim; i += 512) {
    int m = i >> 8, tt = i & 255;
    xi_lds[tt][m] = xg[(size_t)(r0 + m) * Sdim + tt];
  }

  // 3) per-GROUP registration: poll my group's 16 xcd ids (deadlock-safe).
  //    LOCAL mode iff all 16 blocks of this group sit on one physical XCD.
  if (w == 0) {
    int v;
    for (;;) {
      v = __hip_atomic_load(xcds + g * NBLK + (lane & 15), __ATOMIC_RELAXED,
                            __HIP_MEMORY_SCOPE_AGENT);
      if (__all(v != 0)) break;
      __builtin_amdgcn_s_sleep(1);
    }
    int x0 = __shfl(v, 0);
    bool eq = __all(v == x0);
    if (lane == 0) sh_mode = eq ? 1 : 0;
  }
  __syncthreads();
  const bool local_mode = (sh_mode != 0);

  unsigned short* hb0 = hbuf;
  unsigned short* hb1 = hbuf + (size_t)Bdim * Hdim;

  if (local_mode)
    rnn_loop<true>(fc_b, hb0, hb1, gflags, myflag, dout, Bhi, Blo, e2s,
                   redc, redf, fcs, bias2, xi_lds, outbuf, tid, w, lane, quad,
                   l16, r0, n0, v0);
  else
    rnn_loop<false>(fc_b, hb0, hb1, gflags, myflag, dout, Bhi, Blo, e2s,
                    redc, redf, fcs, bias2, xi_lds, outbuf, tid, w, lane, quad,
                    l16, r0, n0, v0);
}

extern "C" void kernel_launch(void* const* d_in, const int* in_sizes, int n_in,
                              void* d_out, int out_size, void* d_ws, size_t ws_size,
                              hipStream_t stream) {
  const int* x = (const int*)d_in[0];
  const float* embed = (const float*)d_in[1];
  const float* Wxh_w = (const float*)d_in[2];
  const float* Wxh_b = (const float*)d_in[3];
  const float* Whh_w = (const float*)d_in[4];
  const float* Whh_b = (const float*)d_in[5];
  const float* fc_w = (const float*)d_in[6];
  const float* fc_b = (const float*)d_in[7];
  float* out = (float*)d_out;

  char* ws = (char*)d_ws;
  float* E2 = (float*)ws;                                   // 512 KB
  unsigned short* hbuf = (unsigned short*)(ws + 524288);    // 1 MB
  int* flags = (int*)(ws + 1572864);                        // 256 x 256B = 64 KB
  int* xcds = (int*)(ws + 1572864 + 65536);                 // 256 ints

  hipMemsetAsync(flags, 0, 256 * FPAD * sizeof(int) + 256 * sizeof(int), stream);
  e2_kernel<<<dim3(Hdim / 16), dim3(256), 0, stream>>>(embed, Wxh_w, E2);
  rnn_kernel<<<dim3(256), dim3(512), 0, stream>>>(x, Whh_w, Wxh_b, Whh_b, fc_w,
                                                  fc_b, E2, hbuf, flags, xcds, out);
}